// Round 1
// baseline (886.428 us; speedup 1.0000x reference)
//
#include <hip/hip_runtime.h>
#include <hip/hip_bf16.h>
#include <math.h>

#define NN 100000
#define EE 1600000
#define HD 128
#define GG 128
#define CC 10
#define SCH 512   // scan chunk (elements per scan block)

// ---------------- CSR build ----------------

__global__ void k_count_deg(const int* __restrict__ dst, int* __restrict__ deg) {
    int i = blockIdx.x * blockDim.x + threadIdx.x;
    if (i < EE) atomicAdd(&deg[dst[i]], 1);
}

__global__ void k_dinv(const int* __restrict__ deg, float* __restrict__ dinv) {
    int i = blockIdx.x * blockDim.x + threadIdx.x;
    if (i < NN) dinv[i] = rsqrtf((float)(deg[i] + 1));  // +1 self loop, always > 0
}

__global__ void k_block_sum(const int* __restrict__ deg, int* __restrict__ bsums) {
    __shared__ int s[SCH];
    int t = threadIdx.x;
    int base = blockIdx.x * SCH;
    s[t] = (base + t < NN) ? deg[base + t] : 0;
    __syncthreads();
    for (int off = SCH / 2; off > 0; off >>= 1) {
        if (t < off) s[t] += s[t + off];
        __syncthreads();
    }
    if (t == 0) bsums[blockIdx.x] = s[0];
}

// single block, exclusive scan of nb (<256) block sums
__global__ void k_scan_bsums(int* __restrict__ bsums, int nb) {
    __shared__ int s[256];
    int t = threadIdx.x;
    int v = (t < nb) ? bsums[t] : 0;
    s[t] = v;
    __syncthreads();
    for (int off = 1; off < 256; off <<= 1) {
        int add = (t >= off) ? s[t - off] : 0;
        __syncthreads();
        s[t] += add;
        __syncthreads();
    }
    if (t < nb) bsums[t] = s[t] - v;  // exclusive
}

__global__ void k_row_start(const int* __restrict__ deg, const int* __restrict__ bsums,
                            int* __restrict__ row_start) {
    __shared__ int s[SCH];
    int t = threadIdx.x;
    int base = blockIdx.x * SCH;
    int v = (base + t < NN) ? deg[base + t] : 0;
    s[t] = v;
    __syncthreads();
    for (int off = 1; off < SCH; off <<= 1) {
        int add = (t >= off) ? s[t - off] : 0;
        __syncthreads();
        s[t] += add;
        __syncthreads();
    }
    int excl = s[t] - v + bsums[blockIdx.x];
    if (base + t < NN) row_start[base + t] = excl;
    if (base + t == NN - 1) row_start[NN] = excl + v;
}

__global__ void k_fill_csr(const int* __restrict__ src, const int* __restrict__ dst,
                           const int* __restrict__ row_start, int* __restrict__ fill,
                           int* __restrict__ col) {
    int i = blockIdx.x * blockDim.x + threadIdx.x;
    if (i < EE) {
        int d = dst[i];
        int pos = row_start[d] + atomicAdd(&fill[d], 1);
        col[pos] = src[i];
    }
}

// ---------------- GEMM: g = dinv ⊙ (A @ W), A:[NN,128] W:[128,128] ----------------
// 128x128 tile per block, 256 threads, 8x8 microtile, BK=32, K=128.

__global__ __launch_bounds__(256) void k_gemm_scale(
    const float* __restrict__ A, const float* __restrict__ W,
    const float* __restrict__ dinv, float* __restrict__ out) {
    __shared__ float As[32 * 132];  // [k][row], stride 132 breaks bank conflicts
    __shared__ float Ws[32 * 132];  // [k][col]
    int t = threadIdx.x;
    int tx = t & 15, ty = t >> 4;
    int r0 = blockIdx.x * 128;

    float acc[8][8];
#pragma unroll
    for (int i = 0; i < 8; ++i)
#pragma unroll
        for (int j = 0; j < 8; ++j) acc[i][j] = 0.f;

    for (int kt = 0; kt < 4; ++kt) {
        int k0 = kt * 32;
        // A tile: 128 rows x 32 k, float4 loads, transpose into As[k][row]
#pragma unroll
        for (int p = 0; p < 4; ++p) {
            int idx = p * 256 + t;
            int row = idx >> 3, q = idx & 7;
            int gr = r0 + row;
            float4 v = make_float4(0.f, 0.f, 0.f, 0.f);
            if (gr < NN) v = *(const float4*)(A + (size_t)gr * HD + k0 + q * 4);
            As[(q * 4 + 0) * 132 + row] = v.x;
            As[(q * 4 + 1) * 132 + row] = v.y;
            As[(q * 4 + 2) * 132 + row] = v.z;
            As[(q * 4 + 3) * 132 + row] = v.w;
        }
        // W tile: 32 k x 128 cols, float4 straight through
#pragma unroll
        for (int p = 0; p < 4; ++p) {
            int idx = p * 256 + t;
            int kk = idx >> 5, q = idx & 31;
            float4 v = *(const float4*)(W + (k0 + kk) * HD + q * 4);
            *(float4*)(Ws + kk * 132 + q * 4) = v;
        }
        __syncthreads();
#pragma unroll 4
        for (int k = 0; k < 32; ++k) {
            float a[8], b[8];
#pragma unroll
            for (int i = 0; i < 8; ++i) a[i] = As[k * 132 + ty + 16 * i];
#pragma unroll
            for (int j = 0; j < 8; ++j) b[j] = Ws[k * 132 + tx + 16 * j];
#pragma unroll
            for (int i = 0; i < 8; ++i)
#pragma unroll
                for (int j = 0; j < 8; ++j) acc[i][j] = fmaf(a[i], b[j], acc[i][j]);
        }
        __syncthreads();
    }

#pragma unroll
    for (int i = 0; i < 8; ++i) {
        int r = r0 + ty + 16 * i;
        if (r < NN) {
            float sc = dinv[r];
#pragma unroll
            for (int j = 0; j < 8; ++j) out[(size_t)r * HD + tx + 16 * j] = acc[i][j] * sc;
        }
    }
}

// ---------------- aggregation: out[d] = relu(dinv[d]*(g[d] + sum_in g[s]) + b) ----------------
// one wave per node, float2 per lane (512B/row per gather)

__global__ __launch_bounds__(256) void k_aggregate(
    const float* __restrict__ g, const int* __restrict__ row_start,
    const int* __restrict__ col, const float* __restrict__ dinv,
    const float* __restrict__ bias, float* __restrict__ out) {
    int node = blockIdx.x * 4 + (threadIdx.x >> 6);
    if (node >= NN) return;
    int lane = threadIdx.x & 63;
    const float2* g2 = (const float2*)g;
    float2 acc = g2[node * 64 + lane];  // self loop
    int e = row_start[node], end = row_start[node + 1];
    for (; e + 4 <= end; e += 4) {
        int s0 = col[e], s1 = col[e + 1], s2 = col[e + 2], s3 = col[e + 3];
        float2 v0 = g2[s0 * 64 + lane];
        float2 v1 = g2[s1 * 64 + lane];
        float2 v2 = g2[s2 * 64 + lane];
        float2 v3 = g2[s3 * 64 + lane];
        acc.x += (v0.x + v1.x) + (v2.x + v3.x);
        acc.y += (v0.y + v1.y) + (v2.y + v3.y);
    }
    for (; e < end; ++e) {
        int s = col[e];
        float2 v = g2[s * 64 + lane];
        acc.x += v.x;
        acc.y += v.y;
    }
    float sc = dinv[node];
    float2 bb = ((const float2*)bias)[lane];
    float2 r;
    r.x = fmaxf(fmaf(acc.x, sc, bb.x), 0.f);
    r.y = fmaxf(fmaf(acc.y, sc, bb.y), 0.f);
    ((float2*)out)[node * 64 + lane] = r;
}

// ---------------- mean pool per graph (batch is sorted) ----------------

__device__ __forceinline__ int lower_bound_i(const int* a, int n, int key) {
    int lo = 0, hi = n;
    while (lo < hi) {
        int mid = (lo + hi) >> 1;
        if (a[mid] < key) lo = mid + 1;
        else hi = mid;
    }
    return lo;
}

__global__ __launch_bounds__(512) void k_pool(const float* __restrict__ h,
                                              const int* __restrict__ batch,
                                              float* __restrict__ pooled) {
    __shared__ float partial[4][HD];
    __shared__ int range[2];
    int t = threadIdx.x, g = blockIdx.x;
    if (t == 0) {
        range[0] = lower_bound_i(batch, NN, g);
        range[1] = lower_bound_i(batch, NN, g + 1);
    }
    __syncthreads();
    int lo = range[0], hi = range[1];
    int feat = t & 127, sl = t >> 7;
    float acc = 0.f;
    for (int r = lo + sl; r < hi; r += 4) acc += h[(size_t)r * HD + feat];
    partial[sl][feat] = acc;
    __syncthreads();
    if (t < HD) {
        float s = partial[0][t] + partial[1][t] + partial[2][t] + partial[3][t];
        float cnt = (float)(hi - lo);
        pooled[g * HD + t] = s / fmaxf(cnt, 1.f);
    }
}

// ---------------- head: relu(pooled@w1+b1) @ w2 + b2 -> log_softmax ----------------

__global__ __launch_bounds__(128) void k_head(const float* __restrict__ pooled,
                                              const float* __restrict__ w1,
                                              const float* __restrict__ b1,
                                              const float* __restrict__ w2,
                                              const float* __restrict__ b2,
                                              float* __restrict__ out) {
    __shared__ float row[HD], hrow[HD], logits[CC];
    int g = blockIdx.x, t = threadIdx.x;
    row[t] = pooled[g * HD + t];
    __syncthreads();
    float acc = b1[t];
    for (int k = 0; k < HD; ++k) acc = fmaf(row[k], w1[k * HD + t], acc);
    hrow[t] = fmaxf(acc, 0.f);
    __syncthreads();
    if (t < CC) {
        float a = b2[t];
        for (int k = 0; k < HD; ++k) a = fmaf(hrow[k], w2[k * CC + t], a);
        logits[t] = a;
    }
    __syncthreads();
    if (t < CC) {
        float m = logits[0];
        for (int i = 1; i < CC; ++i) m = fmaxf(m, logits[i]);
        float s = 0.f;
        for (int i = 0; i < CC; ++i) s += expf(logits[i] - m);
        out[g * CC + t] = logits[t] - m - logf(s);
    }
}

// ---------------- launch ----------------

extern "C" void kernel_launch(void* const* d_in, const int* in_sizes, int n_in,
                              void* d_out, int out_size, void* d_ws, size_t ws_size,
                              hipStream_t stream) {
    const float* x      = (const float*)d_in[0];
    const int*   ei     = (const int*)d_in[1];   // [2,E]: row0=src, row1=dst
    const int*   batch  = (const int*)d_in[2];
    const float* w_init = (const float*)d_in[3];
    const float* b_init = (const float*)d_in[4];
    const float* w_conv = (const float*)d_in[5];  // [2,128,128]
    const float* b_conv = (const float*)d_in[6];  // [2,128]
    const float* w_h1   = (const float*)d_in[7];
    const float* b_h1   = (const float*)d_in[8];
    const float* w_h2   = (const float*)d_in[9];
    const float* b_h2   = (const float*)d_in[10];
    float* out = (float*)d_out;
    (void)b_h1; (void)n_in; (void)in_sizes; (void)out_size; (void)ws_size;

    char* ws = (char*)d_ws;
    size_t off = 0;
    auto alloc = [&](size_t bytes) -> void* {
        void* p = ws + off;
        off += (bytes + 255) & ~(size_t)255;
        return p;
    };
    float* hA        = (float*)alloc((size_t)NN * HD * 4);  // 51.2 MB
    float* hB        = (float*)alloc((size_t)NN * HD * 4);  // 51.2 MB
    float* dinv      = (float*)alloc((size_t)NN * 4);
    int*   deg       = (int*)alloc((size_t)NN * 4);
    int*   fill      = (int*)alloc((size_t)NN * 4);
    int*   row_start = (int*)alloc((size_t)(NN + 1) * 4);
    int*   col       = (int*)alloc((size_t)EE * 4);         // 6.4 MB
    int*   bsums     = (int*)alloc(256 * 4);
    float* pooled    = (float*)alloc((size_t)GG * HD * 4);

    const int* srcp = ei;
    const int* dstp = ei + EE;

    hipMemsetAsync(deg, 0, (size_t)NN * 4, stream);
    hipMemsetAsync(fill, 0, (size_t)NN * 4, stream);

    k_count_deg<<<(EE + 255) / 256, 256, 0, stream>>>(dstp, deg);
    k_dinv<<<(NN + 255) / 256, 256, 0, stream>>>(deg, dinv);

    int NB = (NN + SCH - 1) / SCH;  // 196 <= 256
    k_block_sum<<<NB, SCH, 0, stream>>>(deg, bsums);
    k_scan_bsums<<<1, 256, 0, stream>>>(bsums, NB);
    k_row_start<<<NB, SCH, 0, stream>>>(deg, bsums, row_start);
    k_fill_csr<<<(EE + 255) / 256, 256, 0, stream>>>(srcp, dstp, row_start, fill, col);

    int gemm_grid = (NN + 127) / 128;  // 782
    int agg_grid = (NN + 3) / 4;       // 25000

    // layer 1: x -> hB (gemm+scale) -> hA (aggregate+bias+relu)
    k_gemm_scale<<<gemm_grid, 256, 0, stream>>>(x, w_init, dinv, hB);
    k_aggregate<<<agg_grid, 256, 0, stream>>>(hB, row_start, col, dinv, b_init, hA);
    // layer 2
    k_gemm_scale<<<gemm_grid, 256, 0, stream>>>(hA, w_conv, dinv, hB);
    k_aggregate<<<agg_grid, 256, 0, stream>>>(hB, row_start, col, dinv, b_conv, hA);
    // layer 3
    k_gemm_scale<<<gemm_grid, 256, 0, stream>>>(hA, w_conv + HD * HD, dinv, hB);
    k_aggregate<<<agg_grid, 256, 0, stream>>>(hB, row_start, col, dinv, b_conv + HD, hA);

    k_pool<<<GG, 512, 0, stream>>>(hA, batch, pooled);
    k_head<<<GG, 128, 0, stream>>>(pooled, w_h1, b_h1, w_h2, b_h2, out);
}

// Round 2
// 779.414 us; speedup vs baseline: 1.1373x; 1.1373x over previous
//
#include <hip/hip_runtime.h>
#include <hip/hip_bf16.h>
#include <math.h>

#define NN 100000
#define EE 1600000
#define HD 128
#define GG 128
#define CC 10
#define SCH 512   // scan chunk (elements per scan block)

// ---------------- CSR build ----------------
// Pass 1: degree count + per-edge rank in ONE atomic pass.
__global__ void k_count_rank(const int* __restrict__ dst, int* __restrict__ deg,
                             int* __restrict__ rank) {
    int i = blockIdx.x * blockDim.x + threadIdx.x;
    if (i < EE) rank[i] = atomicAdd(&deg[dst[i]], 1);
}

__global__ void k_dinv(const int* __restrict__ deg, float* __restrict__ dinv) {
    int i = blockIdx.x * blockDim.x + threadIdx.x;
    if (i < NN) dinv[i] = rsqrtf((float)(deg[i] + 1));  // +1 self loop, always > 0
}

__global__ void k_block_sum(const int* __restrict__ deg, int* __restrict__ bsums) {
    __shared__ int s[SCH];
    int t = threadIdx.x;
    int base = blockIdx.x * SCH;
    s[t] = (base + t < NN) ? deg[base + t] : 0;
    __syncthreads();
    for (int off = SCH / 2; off > 0; off >>= 1) {
        if (t < off) s[t] += s[t + off];
        __syncthreads();
    }
    if (t == 0) bsums[blockIdx.x] = s[0];
}

// single block, exclusive scan of nb (<256) block sums
__global__ void k_scan_bsums(int* __restrict__ bsums, int nb) {
    __shared__ int s[256];
    int t = threadIdx.x;
    int v = (t < nb) ? bsums[t] : 0;
    s[t] = v;
    __syncthreads();
    for (int off = 1; off < 256; off <<= 1) {
        int add = (t >= off) ? s[t - off] : 0;
        __syncthreads();
        s[t] += add;
        __syncthreads();
    }
    if (t < nb) bsums[t] = s[t] - v;  // exclusive
}

__global__ void k_row_start(const int* __restrict__ deg, const int* __restrict__ bsums,
                            int* __restrict__ row_start) {
    __shared__ int s[SCH];
    int t = threadIdx.x;
    int base = blockIdx.x * SCH;
    int v = (base + t < NN) ? deg[base + t] : 0;
    s[t] = v;
    __syncthreads();
    for (int off = 1; off < SCH; off <<= 1) {
        int add = (t >= off) ? s[t - off] : 0;
        __syncthreads();
        s[t] += add;
        __syncthreads();
    }
    int excl = s[t] - v + bsums[blockIdx.x];
    if (base + t < NN) row_start[base + t] = excl;
    if (base + t == NN - 1) row_start[NN] = excl + v;
}

// Pass 2: pure scatter, no atomics.
__global__ void k_scatter_col(const int* __restrict__ src, const int* __restrict__ dst,
                              const int* __restrict__ row_start,
                              const int* __restrict__ rank, int* __restrict__ col) {
    int i = blockIdx.x * blockDim.x + threadIdx.x;
    if (i < EE) {
        int d = dst[i];
        col[row_start[d] + rank[i]] = src[i];
    }
}

// ---------------- GEMM: g = dinv ⊙ (A @ W), A:[NN,128] W:[128,128] ----------------
// 128x128 tile per block, 256 threads, 8x8 microtile as 2x2 quads of float4,
// BK=32, K=128. LDS strides 132 floats (16B-aligned rows, <=2-way read conflicts).

#define LDW 132

__global__ __launch_bounds__(256) void k_gemm_scale(
    const float* __restrict__ A, const float* __restrict__ W,
    const float* __restrict__ dinv, float* __restrict__ out) {
    __shared__ float As[32 * LDW];  // [k][row]
    __shared__ float Ws[32 * LDW];  // [k][col]
    int t = threadIdx.x;
    int tx = t & 15, ty = t >> 4;
    int r0 = blockIdx.x * 128;
    int rr[2] = {ty * 4, ty * 4 + 64};
    int cc[2] = {tx * 4, tx * 4 + 64};

    float acc[2][2][4][4];
#pragma unroll
    for (int a = 0; a < 2; ++a)
#pragma unroll
        for (int b = 0; b < 2; ++b)
#pragma unroll
            for (int i = 0; i < 4; ++i)
#pragma unroll
                for (int j = 0; j < 4; ++j) acc[a][b][i][j] = 0.f;

    for (int kt = 0; kt < 4; ++kt) {
        int k0 = kt * 32;
        // A tile: 128 rows x 32 k, float4 loads, transpose into As[k][row]
#pragma unroll
        for (int p = 0; p < 4; ++p) {
            int idx = p * 256 + t;
            int row = idx >> 3, q = idx & 7;
            int gr = r0 + row;
            float4 v = make_float4(0.f, 0.f, 0.f, 0.f);
            if (gr < NN) v = *(const float4*)(A + (size_t)gr * HD + k0 + q * 4);
            As[(q * 4 + 0) * LDW + row] = v.x;
            As[(q * 4 + 1) * LDW + row] = v.y;
            As[(q * 4 + 2) * LDW + row] = v.z;
            As[(q * 4 + 3) * LDW + row] = v.w;
        }
        // W tile: 32 k x 128 cols, float4 straight through
#pragma unroll
        for (int p = 0; p < 4; ++p) {
            int idx = p * 256 + t;
            int kk = idx >> 5, q = idx & 31;
            float4 v = *(const float4*)(W + (size_t)(k0 + kk) * HD + q * 4);
            *(float4*)(Ws + kk * LDW + q * 4) = v;
        }
        __syncthreads();
#pragma unroll 8
        for (int k = 0; k < 32; ++k) {
            float4 a0 = *(const float4*)(As + k * LDW + rr[0]);
            float4 a1 = *(const float4*)(As + k * LDW + rr[1]);
            float4 b0 = *(const float4*)(Ws + k * LDW + cc[0]);
            float4 b1 = *(const float4*)(Ws + k * LDW + cc[1]);
            float av[2][4] = {{a0.x, a0.y, a0.z, a0.w}, {a1.x, a1.y, a1.z, a1.w}};
            float bv[2][4] = {{b0.x, b0.y, b0.z, b0.w}, {b1.x, b1.y, b1.z, b1.w}};
#pragma unroll
            for (int ih = 0; ih < 2; ++ih)
#pragma unroll
                for (int jh = 0; jh < 2; ++jh)
#pragma unroll
                    for (int i = 0; i < 4; ++i)
#pragma unroll
                        for (int j = 0; j < 4; ++j)
                            acc[ih][jh][i][j] = fmaf(av[ih][i], bv[jh][j], acc[ih][jh][i][j]);
        }
        __syncthreads();
    }

#pragma unroll
    for (int ih = 0; ih < 2; ++ih)
#pragma unroll
        for (int i = 0; i < 4; ++i) {
            int r = r0 + rr[ih] + i;
            if (r < NN) {
                float sc = dinv[r];
#pragma unroll
                for (int jh = 0; jh < 2; ++jh) {
                    float4 v;
                    v.x = acc[ih][jh][i][0] * sc;
                    v.y = acc[ih][jh][i][1] * sc;
                    v.z = acc[ih][jh][i][2] * sc;
                    v.w = acc[ih][jh][i][3] * sc;
                    *(float4*)(out + (size_t)r * HD + cc[jh]) = v;
                }
            }
        }
}

// ---------------- aggregation: out[d] = relu(dinv[d]*(g[d] + sum_in g[s]) + b) ----------------
// one wave per node, float2 per lane (512B/row per gather), 8 gathers in flight

__global__ __launch_bounds__(256) void k_aggregate(
    const float* __restrict__ g, const int* __restrict__ row_start,
    const int* __restrict__ col, const float* __restrict__ dinv,
    const float* __restrict__ bias, float* __restrict__ out) {
    int node = blockIdx.x * 4 + (threadIdx.x >> 6);
    if (node >= NN) return;
    int lane = threadIdx.x & 63;
    const float2* g2 = (const float2*)g;
    float2 acc = g2[node * 64 + lane];  // self loop
    int e = row_start[node], end = row_start[node + 1];
    for (; e + 8 <= end; e += 8) {
        int s0 = col[e], s1 = col[e + 1], s2 = col[e + 2], s3 = col[e + 3];
        int s4 = col[e + 4], s5 = col[e + 5], s6 = col[e + 6], s7 = col[e + 7];
        float2 v0 = g2[s0 * 64 + lane];
        float2 v1 = g2[s1 * 64 + lane];
        float2 v2 = g2[s2 * 64 + lane];
        float2 v3 = g2[s3 * 64 + lane];
        float2 v4 = g2[s4 * 64 + lane];
        float2 v5 = g2[s5 * 64 + lane];
        float2 v6 = g2[s6 * 64 + lane];
        float2 v7 = g2[s7 * 64 + lane];
        acc.x += ((v0.x + v1.x) + (v2.x + v3.x)) + ((v4.x + v5.x) + (v6.x + v7.x));
        acc.y += ((v0.y + v1.y) + (v2.y + v3.y)) + ((v4.y + v5.y) + (v6.y + v7.y));
    }
    for (; e < end; ++e) {
        int s = col[e];
        float2 v = g2[s * 64 + lane];
        acc.x += v.x;
        acc.y += v.y;
    }
    float sc = dinv[node];
    float2 bb = ((const float2*)bias)[lane];
    float2 r;
    r.x = fmaxf(fmaf(acc.x, sc, bb.x), 0.f);
    r.y = fmaxf(fmaf(acc.y, sc, bb.y), 0.f);
    ((float2*)out)[node * 64 + lane] = r;
}

// ---------------- mean pool per graph (batch is sorted) ----------------

__device__ __forceinline__ int lower_bound_i(const int* a, int n, int key) {
    int lo = 0, hi = n;
    while (lo < hi) {
        int mid = (lo + hi) >> 1;
        if (a[mid] < key) lo = mid + 1;
        else hi = mid;
    }
    return lo;
}

__global__ __launch_bounds__(512) void k_pool(const float* __restrict__ h,
                                              const int* __restrict__ batch,
                                              float* __restrict__ pooled) {
    __shared__ float partial[4][HD];
    __shared__ int range[2];
    int t = threadIdx.x, g = blockIdx.x;
    if (t == 0) {
        range[0] = lower_bound_i(batch, NN, g);
        range[1] = lower_bound_i(batch, NN, g + 1);
    }
    __syncthreads();
    int lo = range[0], hi = range[1];
    int feat = t & 127, sl = t >> 7;
    float acc = 0.f;
    for (int r = lo + sl; r < hi; r += 4) acc += h[(size_t)r * HD + feat];
    partial[sl][feat] = acc;
    __syncthreads();
    if (t < HD) {
        float s = partial[0][t] + partial[1][t] + partial[2][t] + partial[3][t];
        float cnt = (float)(hi - lo);
        pooled[g * HD + t] = s / fmaxf(cnt, 1.f);
    }
}

// ---------------- head: relu(pooled@w1+b1) @ w2 + b2 -> log_softmax ----------------

__global__ __launch_bounds__(128) void k_head(const float* __restrict__ pooled,
                                              const float* __restrict__ w1,
                                              const float* __restrict__ b1,
                                              const float* __restrict__ w2,
                                              const float* __restrict__ b2,
                                              float* __restrict__ out) {
    __shared__ float row[HD], hrow[HD], logits[CC];
    int g = blockIdx.x, t = threadIdx.x;
    row[t] = pooled[g * HD + t];
    __syncthreads();
    float acc = b1[t];
    for (int k = 0; k < HD; ++k) acc = fmaf(row[k], w1[k * HD + t], acc);
    hrow[t] = fmaxf(acc, 0.f);
    __syncthreads();
    if (t < CC) {
        float a = b2[t];
        for (int k = 0; k < HD; ++k) a = fmaf(hrow[k], w2[k * CC + t], a);
        logits[t] = a;
    }
    __syncthreads();
    if (t < CC) {
        float m = logits[0];
        for (int i = 1; i < CC; ++i) m = fmaxf(m, logits[i]);
        float s = 0.f;
        for (int i = 0; i < CC; ++i) s += expf(logits[i] - m);
        out[g * CC + t] = logits[t] - m - logf(s);
    }
}

// ---------------- launch ----------------

extern "C" void kernel_launch(void* const* d_in, const int* in_sizes, int n_in,
                              void* d_out, int out_size, void* d_ws, size_t ws_size,
                              hipStream_t stream) {
    const float* x      = (const float*)d_in[0];
    const int*   ei     = (const int*)d_in[1];   // [2,E]: row0=src, row1=dst
    const int*   batch  = (const int*)d_in[2];
    const float* w_init = (const float*)d_in[3];
    const float* b_init = (const float*)d_in[4];
    const float* w_conv = (const float*)d_in[5];  // [2,128,128]
    const float* b_conv = (const float*)d_in[6];  // [2,128]
    const float* w_h1   = (const float*)d_in[7];
    const float* b_h1   = (const float*)d_in[8];
    const float* w_h2   = (const float*)d_in[9];
    const float* b_h2   = (const float*)d_in[10];
    float* out = (float*)d_out;
    (void)n_in; (void)in_sizes; (void)out_size; (void)ws_size;

    char* ws = (char*)d_ws;
    size_t off = 0;
    auto alloc = [&](size_t bytes) -> void* {
        void* p = ws + off;
        off += (bytes + 255) & ~(size_t)255;
        return p;
    };
    float* hA        = (float*)alloc((size_t)NN * HD * 4);  // 51.2 MB
    float* hB        = (float*)alloc((size_t)NN * HD * 4);  // 51.2 MB
    float* dinv      = (float*)alloc((size_t)NN * 4);
    int*   deg       = (int*)alloc((size_t)NN * 4);
    int*   rank      = (int*)alloc((size_t)EE * 4);         // 6.4 MB
    int*   row_start = (int*)alloc((size_t)(NN + 1) * 4);
    int*   col       = (int*)alloc((size_t)EE * 4);         // 6.4 MB
    int*   bsums     = (int*)alloc(256 * 4);
    float* pooled    = (float*)alloc((size_t)GG * HD * 4);

    const int* srcp = ei;
    const int* dstp = ei + EE;

    hipMemsetAsync(deg, 0, (size_t)NN * 4, stream);

    k_count_rank<<<(EE + 255) / 256, 256, 0, stream>>>(dstp, deg, rank);
    k_dinv<<<(NN + 255) / 256, 256, 0, stream>>>(deg, dinv);

    int NB = (NN + SCH - 1) / SCH;  // 196 <= 256
    k_block_sum<<<NB, SCH, 0, stream>>>(deg, bsums);
    k_scan_bsums<<<1, 256, 0, stream>>>(bsums, NB);
    k_row_start<<<NB, SCH, 0, stream>>>(deg, bsums, row_start);
    k_scatter_col<<<(EE + 255) / 256, 256, 0, stream>>>(srcp, dstp, row_start, rank, col);

    int gemm_grid = (NN + 127) / 128;  // 782
    int agg_grid = (NN + 3) / 4;       // 25000

    // layer 1: x -> hB (gemm+scale) -> hA (aggregate+bias+relu)
    k_gemm_scale<<<gemm_grid, 256, 0, stream>>>(x, w_init, dinv, hB);
    k_aggregate<<<agg_grid, 256, 0, stream>>>(hB, row_start, col, dinv, b_init, hA);
    // layer 2
    k_gemm_scale<<<gemm_grid, 256, 0, stream>>>(hA, w_conv, dinv, hB);
    k_aggregate<<<agg_grid, 256, 0, stream>>>(hB, row_start, col, dinv, b_conv, hA);
    // layer 3
    k_gemm_scale<<<gemm_grid, 256, 0, stream>>>(hA, w_conv + HD * HD, dinv, hB);
    k_aggregate<<<agg_grid, 256, 0, stream>>>(hB, row_start, col, dinv, b_conv + HD, hA);

    k_pool<<<GG, 512, 0, stream>>>(hA, batch, pooled);
    k_head<<<GG, 128, 0, stream>>>(pooled, w_h1, b_h1, w_h2, b_h2, out);
}

// Round 3
// 648.191 us; speedup vs baseline: 1.3675x; 1.2024x over previous
//
#include <hip/hip_runtime.h>
#include <hip/hip_bf16.h>
#include <math.h>

#define NN 100000
#define EE 1600000
#define HD 128
#define GG 128
#define CC 10
#define SCH 512   // scan chunk (elements per scan block)

// bf16 helpers (RNE)
__device__ __forceinline__ unsigned short f2bf(float f) {
    union { float f; unsigned u; } a; a.f = f;
    unsigned r = a.u + 0x7fff + ((a.u >> 16) & 1);
    return (unsigned short)(r >> 16);
}
__device__ __forceinline__ float bflo(unsigned u) {
    union { unsigned u; float f; } a; a.u = u << 16; return a.f;
}
__device__ __forceinline__ float bfhi(unsigned u) {
    union { unsigned u; float f; } a; a.u = u & 0xffff0000u; return a.f;
}

// ---------------- CSR build ----------------
__global__ void k_count_rank(const int* __restrict__ dst, int* __restrict__ deg,
                             int* __restrict__ rank) {
    int i = blockIdx.x * blockDim.x + threadIdx.x;
    if (i < EE) rank[i] = atomicAdd(&deg[dst[i]], 1);
}

__global__ void k_dinv(const int* __restrict__ deg, float* __restrict__ dinv) {
    int i = blockIdx.x * blockDim.x + threadIdx.x;
    if (i < NN) dinv[i] = rsqrtf((float)(deg[i] + 1));  // +1 self loop, always > 0
}

__global__ void k_block_sum(const int* __restrict__ deg, int* __restrict__ bsums) {
    __shared__ int s[SCH];
    int t = threadIdx.x;
    int base = blockIdx.x * SCH;
    s[t] = (base + t < NN) ? deg[base + t] : 0;
    __syncthreads();
    for (int off = SCH / 2; off > 0; off >>= 1) {
        if (t < off) s[t] += s[t + off];
        __syncthreads();
    }
    if (t == 0) bsums[blockIdx.x] = s[0];
}

__global__ void k_scan_bsums(int* __restrict__ bsums, int nb) {
    __shared__ int s[256];
    int t = threadIdx.x;
    int v = (t < nb) ? bsums[t] : 0;
    s[t] = v;
    __syncthreads();
    for (int off = 1; off < 256; off <<= 1) {
        int add = (t >= off) ? s[t - off] : 0;
        __syncthreads();
        s[t] += add;
        __syncthreads();
    }
    if (t < nb) bsums[t] = s[t] - v;  // exclusive
}

__global__ void k_row_start(const int* __restrict__ deg, const int* __restrict__ bsums,
                            int* __restrict__ row_start) {
    __shared__ int s[SCH];
    int t = threadIdx.x;
    int base = blockIdx.x * SCH;
    int v = (base + t < NN) ? deg[base + t] : 0;
    s[t] = v;
    __syncthreads();
    for (int off = 1; off < SCH; off <<= 1) {
        int add = (t >= off) ? s[t - off] : 0;
        __syncthreads();
        s[t] += add;
        __syncthreads();
    }
    int excl = s[t] - v + bsums[blockIdx.x];
    if (base + t < NN) row_start[base + t] = excl;
    if (base + t == NN - 1) row_start[NN] = excl + v;
}

__global__ void k_scatter_col(const int* __restrict__ src, const int* __restrict__ dst,
                              const int* __restrict__ row_start,
                              const int* __restrict__ rank, int* __restrict__ col) {
    int i = blockIdx.x * blockDim.x + threadIdx.x;
    if (i < EE) {
        int d = dst[i];
        col[row_start[d] + rank[i]] = src[i];
    }
}

// ---------------- GEMM: g_bf16 = bf16(dinv ⊙ (A @ W)), A:[NN,128] f32, W:[128,128] ----------------
// 128x128 tile per block, 256 threads, 2x2 quads of float4 microtile, BK=32.

#define LDW 132

__global__ __launch_bounds__(256) void k_gemm_scale(
    const float* __restrict__ A, const float* __restrict__ W,
    const float* __restrict__ dinv, unsigned short* __restrict__ out_bf) {
    __shared__ float As[32 * LDW];  // [k][row]
    __shared__ float Ws[32 * LDW];  // [k][col]
    int t = threadIdx.x;
    int tx = t & 15, ty = t >> 4;
    int r0 = blockIdx.x * 128;
    int rr[2] = {ty * 4, ty * 4 + 64};
    int cc[2] = {tx * 4, tx * 4 + 64};

    float acc[2][2][4][4];
#pragma unroll
    for (int a = 0; a < 2; ++a)
#pragma unroll
        for (int b = 0; b < 2; ++b)
#pragma unroll
            for (int i = 0; i < 4; ++i)
#pragma unroll
                for (int j = 0; j < 4; ++j) acc[a][b][i][j] = 0.f;

    for (int kt = 0; kt < 4; ++kt) {
        int k0 = kt * 32;
#pragma unroll
        for (int p = 0; p < 4; ++p) {
            int idx = p * 256 + t;
            int row = idx >> 3, q = idx & 7;
            int gr = r0 + row;
            float4 v = make_float4(0.f, 0.f, 0.f, 0.f);
            if (gr < NN) v = *(const float4*)(A + (size_t)gr * HD + k0 + q * 4);
            As[(q * 4 + 0) * LDW + row] = v.x;
            As[(q * 4 + 1) * LDW + row] = v.y;
            As[(q * 4 + 2) * LDW + row] = v.z;
            As[(q * 4 + 3) * LDW + row] = v.w;
        }
#pragma unroll
        for (int p = 0; p < 4; ++p) {
            int idx = p * 256 + t;
            int kk = idx >> 5, q = idx & 31;
            float4 v = *(const float4*)(W + (size_t)(k0 + kk) * HD + q * 4);
            *(float4*)(Ws + kk * LDW + q * 4) = v;
        }
        __syncthreads();
#pragma unroll 8
        for (int k = 0; k < 32; ++k) {
            float4 a0 = *(const float4*)(As + k * LDW + rr[0]);
            float4 a1 = *(const float4*)(As + k * LDW + rr[1]);
            float4 b0 = *(const float4*)(Ws + k * LDW + cc[0]);
            float4 b1 = *(const float4*)(Ws + k * LDW + cc[1]);
            float av[2][4] = {{a0.x, a0.y, a0.z, a0.w}, {a1.x, a1.y, a1.z, a1.w}};
            float bv[2][4] = {{b0.x, b0.y, b0.z, b0.w}, {b1.x, b1.y, b1.z, b1.w}};
#pragma unroll
            for (int ih = 0; ih < 2; ++ih)
#pragma unroll
                for (int jh = 0; jh < 2; ++jh)
#pragma unroll
                    for (int i = 0; i < 4; ++i)
#pragma unroll
                        for (int j = 0; j < 4; ++j)
                            acc[ih][jh][i][j] = fmaf(av[ih][i], bv[jh][j], acc[ih][jh][i][j]);
        }
        __syncthreads();
    }

#pragma unroll
    for (int ih = 0; ih < 2; ++ih)
#pragma unroll
        for (int i = 0; i < 4; ++i) {
            int r = r0 + rr[ih] + i;
            if (r < NN) {
                float sc = dinv[r];
#pragma unroll
                for (int jh = 0; jh < 2; ++jh) {
                    ushort4 v;
                    v.x = f2bf(acc[ih][jh][i][0] * sc);
                    v.y = f2bf(acc[ih][jh][i][1] * sc);
                    v.z = f2bf(acc[ih][jh][i][2] * sc);
                    v.w = f2bf(acc[ih][jh][i][3] * sc);
                    *(ushort4*)(out_bf + (size_t)r * HD + cc[jh]) = v;
                }
            }
        }
}

// ---------------- aggregation: out[d] = relu(dinv[d]*(g[d] + sum_in g[s]) + b) ----------------
// g in bf16: each lane gathers one uint (2 features, 4B) per row -> 256B/row.

__global__ __launch_bounds__(256) void k_aggregate(
    const unsigned int* __restrict__ gbf, const int* __restrict__ row_start,
    const int* __restrict__ col, const float* __restrict__ dinv,
    const float* __restrict__ bias, float* __restrict__ out) {
    int node = blockIdx.x * 4 + (threadIdx.x >> 6);
    if (node >= NN) return;
    int lane = threadIdx.x & 63;
    unsigned int su = gbf[node * 64 + lane];  // self loop
    float ax = bflo(su), ay = bfhi(su);
    int e = row_start[node], end = row_start[node + 1];
    for (; e + 8 <= end; e += 8) {
        int s0 = col[e], s1 = col[e + 1], s2 = col[e + 2], s3 = col[e + 3];
        int s4 = col[e + 4], s5 = col[e + 5], s6 = col[e + 6], s7 = col[e + 7];
        unsigned int u0 = gbf[s0 * 64 + lane];
        unsigned int u1 = gbf[s1 * 64 + lane];
        unsigned int u2 = gbf[s2 * 64 + lane];
        unsigned int u3 = gbf[s3 * 64 + lane];
        unsigned int u4 = gbf[s4 * 64 + lane];
        unsigned int u5 = gbf[s5 * 64 + lane];
        unsigned int u6 = gbf[s6 * 64 + lane];
        unsigned int u7 = gbf[s7 * 64 + lane];
        ax += ((bflo(u0) + bflo(u1)) + (bflo(u2) + bflo(u3))) +
              ((bflo(u4) + bflo(u5)) + (bflo(u6) + bflo(u7)));
        ay += ((bfhi(u0) + bfhi(u1)) + (bfhi(u2) + bfhi(u3))) +
              ((bfhi(u4) + bfhi(u5)) + (bfhi(u6) + bfhi(u7)));
    }
    for (; e < end; ++e) {
        unsigned int u = gbf[col[e] * 64 + lane];
        ax += bflo(u);
        ay += bfhi(u);
    }
    float sc = dinv[node];
    float2 bb = ((const float2*)bias)[lane];
    float2 r;
    r.x = fmaxf(fmaf(ax, sc, bb.x), 0.f);
    r.y = fmaxf(fmaf(ay, sc, bb.y), 0.f);
    ((float2*)out)[node * 64 + lane] = r;
}

// ---------------- mean pool per graph (batch is sorted) ----------------

__device__ __forceinline__ int lower_bound_i(const int* a, int n, int key) {
    int lo = 0, hi = n;
    while (lo < hi) {
        int mid = (lo + hi) >> 1;
        if (a[mid] < key) lo = mid + 1;
        else hi = mid;
    }
    return lo;
}

__global__ __launch_bounds__(512) void k_pool(const float* __restrict__ h,
                                              const int* __restrict__ batch,
                                              float* __restrict__ pooled) {
    __shared__ float partial[4][HD];
    __shared__ int range[2];
    int t = threadIdx.x, g = blockIdx.x;
    if (t == 0) {
        range[0] = lower_bound_i(batch, NN, g);
        range[1] = lower_bound_i(batch, NN, g + 1);
    }
    __syncthreads();
    int lo = range[0], hi = range[1];
    int feat = t & 127, sl = t >> 7;
    float acc = 0.f;
    for (int r = lo + sl; r < hi; r += 4) acc += h[(size_t)r * HD + feat];
    partial[sl][feat] = acc;
    __syncthreads();
    if (t < HD) {
        float s = partial[0][t] + partial[1][t] + partial[2][t] + partial[3][t];
        float cnt = (float)(hi - lo);
        pooled[g * HD + t] = s / fmaxf(cnt, 1.f);
    }
}

// ---------------- head ----------------

__global__ __launch_bounds__(128) void k_head(const float* __restrict__ pooled,
                                              const float* __restrict__ w1,
                                              const float* __restrict__ b1,
                                              const float* __restrict__ w2,
                                              const float* __restrict__ b2,
                                              float* __restrict__ out) {
    __shared__ float row[HD], hrow[HD], logits[CC];
    int g = blockIdx.x, t = threadIdx.x;
    row[t] = pooled[g * HD + t];
    __syncthreads();
    float acc = b1[t];
    for (int k = 0; k < HD; ++k) acc = fmaf(row[k], w1[k * HD + t], acc);
    hrow[t] = fmaxf(acc, 0.f);
    __syncthreads();
    if (t < CC) {
        float a = b2[t];
        for (int k = 0; k < HD; ++k) a = fmaf(hrow[k], w2[k * CC + t], a);
        logits[t] = a;
    }
    __syncthreads();
    if (t < CC) {
        float m = logits[0];
        for (int i = 1; i < CC; ++i) m = fmaxf(m, logits[i]);
        float s = 0.f;
        for (int i = 0; i < CC; ++i) s += expf(logits[i] - m);
        out[g * CC + t] = logits[t] - m - logf(s);
    }
}

// ---------------- launch ----------------

extern "C" void kernel_launch(void* const* d_in, const int* in_sizes, int n_in,
                              void* d_out, int out_size, void* d_ws, size_t ws_size,
                              hipStream_t stream) {
    const float* x      = (const float*)d_in[0];
    const int*   ei     = (const int*)d_in[1];   // [2,E]: row0=src, row1=dst
    const int*   batch  = (const int*)d_in[2];
    const float* w_init = (const float*)d_in[3];
    const float* b_init = (const float*)d_in[4];
    const float* w_conv = (const float*)d_in[5];  // [2,128,128]
    const float* b_conv = (const float*)d_in[6];  // [2,128]
    const float* w_h1   = (const float*)d_in[7];
    const float* b_h1   = (const float*)d_in[8];
    const float* w_h2   = (const float*)d_in[9];
    const float* b_h2   = (const float*)d_in[10];
    float* out = (float*)d_out;
    (void)n_in; (void)in_sizes; (void)out_size; (void)ws_size;

    char* ws = (char*)d_ws;
    size_t off = 0;
    auto alloc = [&](size_t bytes) -> void* {
        void* p = ws + off;
        off += (bytes + 255) & ~(size_t)255;
        return p;
    };
    float*          hA        = (float*)alloc((size_t)NN * HD * 4);   // 51.2 MB (f32 node state)
    unsigned short* gbf       = (unsigned short*)alloc((size_t)NN * HD * 2);  // 25.6 MB (bf16 messages)
    float*          dinv      = (float*)alloc((size_t)NN * 4);
    int*            deg       = (int*)alloc((size_t)NN * 4);
    int*            rank      = (int*)alloc((size_t)EE * 4);          // 6.4 MB
    int*            row_start = (int*)alloc((size_t)(NN + 1) * 4);
    int*            col       = (int*)alloc((size_t)EE * 4);          // 6.4 MB
    int*            bsums     = (int*)alloc(256 * 4);
    float*          pooled    = (float*)alloc((size_t)GG * HD * 4);

    const int* srcp = ei;
    const int* dstp = ei + EE;

    hipMemsetAsync(deg, 0, (size_t)NN * 4, stream);

    k_count_rank<<<(EE + 255) / 256, 256, 0, stream>>>(dstp, deg, rank);
    k_dinv<<<(NN + 255) / 256, 256, 0, stream>>>(deg, dinv);

    int NB = (NN + SCH - 1) / SCH;  // 196 <= 256
    k_block_sum<<<NB, SCH, 0, stream>>>(deg, bsums);
    k_scan_bsums<<<1, 256, 0, stream>>>(bsums, NB);
    k_row_start<<<NB, SCH, 0, stream>>>(deg, bsums, row_start);
    k_scatter_col<<<(EE + 255) / 256, 256, 0, stream>>>(srcp, dstp, row_start, rank, col);

    int gemm_grid = (NN + 127) / 128;  // 782
    int agg_grid = (NN + 3) / 4;       // 25000

    // layer 1: x -> gbf (gemm+scale+bf16) -> hA (aggregate+bias+relu)
    k_gemm_scale<<<gemm_grid, 256, 0, stream>>>(x, w_init, dinv, gbf);
    k_aggregate<<<agg_grid, 256, 0, stream>>>((const unsigned int*)gbf, row_start, col, dinv, b_init, hA);
    // layer 2
    k_gemm_scale<<<gemm_grid, 256, 0, stream>>>(hA, w_conv, dinv, gbf);
    k_aggregate<<<agg_grid, 256, 0, stream>>>((const unsigned int*)gbf, row_start, col, dinv, b_conv, hA);
    // layer 3
    k_gemm_scale<<<gemm_grid, 256, 0, stream>>>(hA, w_conv + HD * HD, dinv, gbf);
    k_aggregate<<<agg_grid, 256, 0, stream>>>((const unsigned int*)gbf, row_start, col, dinv, b_conv + HD, hA);

    k_pool<<<GG, 512, 0, stream>>>(hA, batch, pooled);
    k_head<<<GG, 128, 0, stream>>>(pooled, w_h1, b_h1, w_h2, b_h2, out);
}

// Round 4
// 575.381 us; speedup vs baseline: 1.5406x; 1.1265x over previous
//
#include <hip/hip_runtime.h>
#include <hip/hip_bf16.h>
#include <math.h>

#define NN 100000
#define EE 1600000
#define HD 128
#define GG 128
#define CC 10
#define SCH 512   // scan chunk

typedef __attribute__((ext_vector_type(8))) short short8;
typedef __attribute__((ext_vector_type(4))) float f32x4;

// bf16 helpers (RNE)
__device__ __forceinline__ unsigned short f2bf(float f) {
    union { float f; unsigned u; } a; a.f = f;
    unsigned r = a.u + 0x7fff + ((a.u >> 16) & 1);
    return (unsigned short)(r >> 16);
}
__device__ __forceinline__ float bflo(unsigned u) {
    union { unsigned u; float f; } a; a.u = u << 16; return a.f;
}
__device__ __forceinline__ float bfhi(unsigned u) {
    union { unsigned u; float f; } a; a.u = u & 0xffff0000u; return a.f;
}
__device__ __forceinline__ float bfu(unsigned short u) {
    union { unsigned u; float f; } a; a.u = ((unsigned)u) << 16; return a.f;
}

// ---------------- CSR build ----------------
__global__ void k_count_rank(const int* __restrict__ dst, int* __restrict__ deg,
                             int* __restrict__ rank) {
    int i = blockIdx.x * blockDim.x + threadIdx.x;
    if (i < EE) rank[i] = atomicAdd(&deg[dst[i]], 1);
}

__global__ void k_dinv(const int* __restrict__ deg, float* __restrict__ dinv) {
    int i = blockIdx.x * blockDim.x + threadIdx.x;
    if (i < NN) dinv[i] = rsqrtf((float)(deg[i] + 1));
}

__global__ void k_block_sum(const int* __restrict__ deg, int* __restrict__ bsums) {
    __shared__ int s[SCH];
    int t = threadIdx.x;
    int base = blockIdx.x * SCH;
    s[t] = (base + t < NN) ? deg[base + t] : 0;
    __syncthreads();
    for (int off = SCH / 2; off > 0; off >>= 1) {
        if (t < off) s[t] += s[t + off];
        __syncthreads();
    }
    if (t == 0) bsums[blockIdx.x] = s[0];
}

__global__ void k_scan_bsums(int* __restrict__ bsums, int nb) {
    __shared__ int s[256];
    int t = threadIdx.x;
    int v = (t < nb) ? bsums[t] : 0;
    s[t] = v;
    __syncthreads();
    for (int off = 1; off < 256; off <<= 1) {
        int add = (t >= off) ? s[t - off] : 0;
        __syncthreads();
        s[t] += add;
        __syncthreads();
    }
    if (t < nb) bsums[t] = s[t] - v;  // exclusive
}

__global__ void k_row_start(const int* __restrict__ deg, const int* __restrict__ bsums,
                            int* __restrict__ row_start) {
    __shared__ int s[SCH];
    int t = threadIdx.x;
    int base = blockIdx.x * SCH;
    int v = (base + t < NN) ? deg[base + t] : 0;
    s[t] = v;
    __syncthreads();
    for (int off = 1; off < SCH; off <<= 1) {
        int add = (t >= off) ? s[t - off] : 0;
        __syncthreads();
        s[t] += add;
        __syncthreads();
    }
    int excl = s[t] - v + bsums[blockIdx.x];
    if (base + t < NN) row_start[base + t] = excl;
    if (base + t == NN - 1) row_start[NN] = excl + v;
}

__global__ void k_scatter_col(const int* __restrict__ src, const int* __restrict__ dst,
                              const int* __restrict__ row_start,
                              const int* __restrict__ rank, int* __restrict__ col) {
    int i = blockIdx.x * blockDim.x + threadIdx.x;
    if (i < EE) {
        int d = dst[i];
        col[row_start[d] + rank[i]] = src[i];
    }
}

// ---------------- prep: x -> bf16, W -> bf16 transposed ----------------

__global__ void k_cast_bf(const float* __restrict__ x, unsigned short* __restrict__ xb) {
    int i = blockIdx.x * 256 + threadIdx.x;  // one float4 per thread
    float4 v = ((const float4*)x)[i];
    ushort4 o;
    o.x = f2bf(v.x); o.y = f2bf(v.y); o.z = f2bf(v.z); o.w = f2bf(v.w);
    ((ushort4*)xb)[i] = o;
}

// Wt[mat][n][k] = bf16(W[mat][k][n])
__global__ void k_prep_w(const float* __restrict__ w0, const float* __restrict__ w1,
                         const float* __restrict__ w2, unsigned short* __restrict__ Wt) {
    int b = blockIdx.x;
    int mat = b >> 6;
    int idx = (b & 63) * 256 + threadIdx.x;
    int k = idx >> 7, n = idx & 127;
    const float* Wm = (mat == 0) ? w0 : ((mat == 1) ? w1 : w2);
    Wt[mat * 16384 + n * 128 + k] = f2bf(Wm[k * 128 + n]);
}

// ---------------- GEMM (MFMA bf16): gbf = bf16(dinv ⊙ (A @ W)) ----------------
// A: [NN][128] bf16, Wt: [128 n][128 k] bf16 (pre-transposed). 128x128 tile/block,
// 4 waves, each wave a 64x64 quadrant via 4x4 grid of 16x16x32 MFMA tiles.

#define LDK 136  // ushort stride: 272B rows -> 2-way-free LDS bank pattern

__global__ __launch_bounds__(256) void k_gemm_mfma(
    const unsigned short* __restrict__ A, const unsigned short* __restrict__ Wt,
    const float* __restrict__ dinv, unsigned short* __restrict__ out_bf) {
    __shared__ unsigned short As[128 * LDK];  // A tile [row][k]; reused as C tile [row][col]
    __shared__ unsigned short Ws[128 * LDK];  // Wt tile [n][k]
    __shared__ float dv[128];
    int t = threadIdx.x;
    int r0 = blockIdx.x * 128;

    // stage A (rows r0..r0+127, all 128 k) and Wt; 16B chunks, 8 per thread
#pragma unroll
    for (int p = 0; p < 8; ++p) {
        int chunk = p * 256 + t;
        int row = chunk >> 4, kc = chunk & 15;
        uint4 v = make_uint4(0u, 0u, 0u, 0u);
        if (r0 + row < NN) v = *(const uint4*)(A + (size_t)(r0 + row) * HD + kc * 8);
        *(uint4*)(As + row * LDK + kc * 8) = v;
        uint4 w = *(const uint4*)(Wt + (size_t)row * HD + kc * 8);
        *(uint4*)(Ws + row * LDK + kc * 8) = w;
    }
    if (t < 128) dv[t] = (r0 + t < NN) ? dinv[r0 + t] : 0.f;
    __syncthreads();

    int wave = t >> 6, lane = t & 63, quad = lane >> 4, l16 = lane & 15;
    int wr = (wave >> 1) * 64, wc = (wave & 1) * 64;

    f32x4 acc[4][4];
#pragma unroll
    for (int i = 0; i < 4; ++i)
#pragma unroll
        for (int j = 0; j < 4; ++j) acc[i][j] = (f32x4){0.f, 0.f, 0.f, 0.f};

#pragma unroll
    for (int kk = 0; kk < 4; ++kk) {
        int k0 = kk * 32 + quad * 8;
        short8 af[4], bfr[4];
#pragma unroll
        for (int i = 0; i < 4; ++i)
            af[i] = *(const short8*)(As + (wr + i * 16 + l16) * LDK + k0);
#pragma unroll
        for (int j = 0; j < 4; ++j)
            bfr[j] = *(const short8*)(Ws + (wc + j * 16 + l16) * LDK + k0);
#pragma unroll
        for (int i = 0; i < 4; ++i)
#pragma unroll
            for (int j = 0; j < 4; ++j)
                acc[i][j] = __builtin_amdgcn_mfma_f32_16x16x32_bf16(af[i], bfr[j], acc[i][j], 0, 0, 0);
    }
    __syncthreads();  // all LDS reads done; reuse As as C tile

    // epilogue: scale by dinv, bf16, bounce through LDS for coalesced stores
#pragma unroll
    for (int i = 0; i < 4; ++i) {
        int lr = wr + i * 16 + quad * 4;
#pragma unroll
        for (int reg = 0; reg < 4; ++reg) {
            float sc = dv[lr + reg];
#pragma unroll
            for (int j = 0; j < 4; ++j)
                As[(lr + reg) * LDK + wc + j * 16 + l16] = f2bf(acc[i][j][reg] * sc);
        }
    }
    __syncthreads();

    int row = t >> 1, half = t & 1;
    if (r0 + row < NN) {
        unsigned short* dp = out_bf + (size_t)(r0 + row) * HD + half * 64;
        const unsigned short* sp = As + row * LDK + half * 64;
#pragma unroll
        for (int q = 0; q < 8; ++q)
            *(uint4*)(dp + q * 8) = *(const uint4*)(sp + q * 8);
    }
}

// ---------------- aggregation: out = bf16(relu(dinv[d]*(g[d]+sum g[s]) + b)) ----------------

__global__ __launch_bounds__(256) void k_aggregate(
    const unsigned int* __restrict__ gbf, const int* __restrict__ row_start,
    const int* __restrict__ col, const float* __restrict__ dinv,
    const float* __restrict__ bias, unsigned int* __restrict__ out) {
    int node = blockIdx.x * 4 + (threadIdx.x >> 6);
    if (node >= NN) return;
    int lane = threadIdx.x & 63;
    unsigned int su = gbf[node * 64 + lane];  // self loop
    float ax = bflo(su), ay = bfhi(su);
    int e = row_start[node], end = row_start[node + 1];
    for (; e + 8 <= end; e += 8) {
        int s0 = col[e], s1 = col[e + 1], s2 = col[e + 2], s3 = col[e + 3];
        int s4 = col[e + 4], s5 = col[e + 5], s6 = col[e + 6], s7 = col[e + 7];
        unsigned int u0 = gbf[s0 * 64 + lane];
        unsigned int u1 = gbf[s1 * 64 + lane];
        unsigned int u2 = gbf[s2 * 64 + lane];
        unsigned int u3 = gbf[s3 * 64 + lane];
        unsigned int u4 = gbf[s4 * 64 + lane];
        unsigned int u5 = gbf[s5 * 64 + lane];
        unsigned int u6 = gbf[s6 * 64 + lane];
        unsigned int u7 = gbf[s7 * 64 + lane];
        ax += ((bflo(u0) + bflo(u1)) + (bflo(u2) + bflo(u3))) +
              ((bflo(u4) + bflo(u5)) + (bflo(u6) + bflo(u7)));
        ay += ((bfhi(u0) + bfhi(u1)) + (bfhi(u2) + bfhi(u3))) +
              ((bfhi(u4) + bfhi(u5)) + (bfhi(u6) + bfhi(u7)));
    }
    for (; e < end; ++e) {
        unsigned int u = gbf[col[e] * 64 + lane];
        ax += bflo(u);
        ay += bfhi(u);
    }
    float sc = dinv[node];
    float2 bb = ((const float2*)bias)[lane];
    float rx = fmaxf(fmaf(ax, sc, bb.x), 0.f);
    float ry = fmaxf(fmaf(ay, sc, bb.y), 0.f);
    out[node * 64 + lane] = (unsigned)f2bf(rx) | ((unsigned)f2bf(ry) << 16);
}

// ---------------- mean pool per graph (batch sorted), bf16 input ----------------

__device__ __forceinline__ int lower_bound_i(const int* a, int n, int key) {
    int lo = 0, hi = n;
    while (lo < hi) {
        int mid = (lo + hi) >> 1;
        if (a[mid] < key) lo = mid + 1;
        else hi = mid;
    }
    return lo;
}

__global__ __launch_bounds__(512) void k_pool(const unsigned short* __restrict__ h,
                                              const int* __restrict__ batch,
                                              float* __restrict__ pooled) {
    __shared__ float partial[4][HD];
    __shared__ int range[2];
    int t = threadIdx.x, g = blockIdx.x;
    if (t == 0) {
        range[0] = lower_bound_i(batch, NN, g);
        range[1] = lower_bound_i(batch, NN, g + 1);
    }
    __syncthreads();
    int lo = range[0], hi = range[1];
    int feat = t & 127, sl = t >> 7;
    float acc = 0.f;
    for (int r = lo + sl; r < hi; r += 4) acc += bfu(h[(size_t)r * HD + feat]);
    partial[sl][feat] = acc;
    __syncthreads();
    if (t < HD) {
        float s = partial[0][t] + partial[1][t] + partial[2][t] + partial[3][t];
        float cnt = (float)(hi - lo);
        pooled[g * HD + t] = s / fmaxf(cnt, 1.f);
    }
}

// ---------------- head ----------------

__global__ __launch_bounds__(128) void k_head(const float* __restrict__ pooled,
                                              const float* __restrict__ w1,
                                              const float* __restrict__ b1,
                                              const float* __restrict__ w2,
                                              const float* __restrict__ b2,
                                              float* __restrict__ out) {
    __shared__ float row[HD], hrow[HD], logits[CC];
    int g = blockIdx.x, t = threadIdx.x;
    row[t] = pooled[g * HD + t];
    __syncthreads();
    float acc = b1[t];
    for (int k = 0; k < HD; ++k) acc = fmaf(row[k], w1[k * HD + t], acc);
    hrow[t] = fmaxf(acc, 0.f);
    __syncthreads();
    if (t < CC) {
        float a = b2[t];
        for (int k = 0; k < HD; ++k) a = fmaf(hrow[k], w2[k * CC + t], a);
        logits[t] = a;
    }
    __syncthreads();
    if (t < CC) {
        float m = logits[0];
        for (int i = 1; i < CC; ++i) m = fmaxf(m, logits[i]);
        float s = 0.f;
        for (int i = 0; i < CC; ++i) s += expf(logits[i] - m);
        out[g * CC + t] = logits[t] - m - logf(s);
    }
}

// ---------------- launch ----------------

extern "C" void kernel_launch(void* const* d_in, const int* in_sizes, int n_in,
                              void* d_out, int out_size, void* d_ws, size_t ws_size,
                              hipStream_t stream) {
    const float* x      = (const float*)d_in[0];
    const int*   ei     = (const int*)d_in[1];   // [2,E]: row0=src, row1=dst
    const int*   batch  = (const int*)d_in[2];
    const float* w_init = (const float*)d_in[3];
    const float* b_init = (const float*)d_in[4];
    const float* w_conv = (const float*)d_in[5];  // [2,128,128]
    const float* b_conv = (const float*)d_in[6];  // [2,128]
    const float* w_h1   = (const float*)d_in[7];
    const float* b_h1   = (const float*)d_in[8];
    const float* w_h2   = (const float*)d_in[9];
    const float* b_h2   = (const float*)d_in[10];
    float* out = (float*)d_out;
    (void)n_in; (void)in_sizes; (void)out_size; (void)ws_size;

    char* ws = (char*)d_ws;
    size_t off = 0;
    auto alloc = [&](size_t bytes) -> void* {
        void* p = ws + off;
        off += (bytes + 255) & ~(size_t)255;
        return p;
    };
    unsigned short* hAbf      = (unsigned short*)alloc((size_t)NN * HD * 2);  // bf16 node state
    unsigned short* gbf       = (unsigned short*)alloc((size_t)NN * HD * 2);  // bf16 messages
    unsigned short* xb        = (unsigned short*)alloc((size_t)NN * HD * 2);  // bf16 x
    unsigned short* Wt        = (unsigned short*)alloc(3 * 16384 * 2);        // bf16 W^T x3
    float*          dinv      = (float*)alloc((size_t)NN * 4);
    int*            deg       = (int*)alloc((size_t)NN * 4);
    int*            rank      = (int*)alloc((size_t)EE * 4);
    int*            row_start = (int*)alloc((size_t)(NN + 1) * 4);
    int*            col       = (int*)alloc((size_t)EE * 4);
    int*            bsums     = (int*)alloc(256 * 4);
    float*          pooled    = (float*)alloc((size_t)GG * HD * 4);

    const int* srcp = ei;
    const int* dstp = ei + EE;

    hipMemsetAsync(deg, 0, (size_t)NN * 4, stream);

    k_count_rank<<<(EE + 255) / 256, 256, 0, stream>>>(dstp, deg, rank);
    k_dinv<<<(NN + 255) / 256, 256, 0, stream>>>(deg, dinv);

    int NB = (NN + SCH - 1) / SCH;  // 196
    k_block_sum<<<NB, SCH, 0, stream>>>(deg, bsums);
    k_scan_bsums<<<1, 256, 0, stream>>>(bsums, NB);
    k_row_start<<<NB, SCH, 0, stream>>>(deg, bsums, row_start);
    k_scatter_col<<<(EE + 255) / 256, 256, 0, stream>>>(srcp, dstp, row_start, rank, col);

    k_cast_bf<<<(NN * HD / 4) / 256 + 1, 256, 0, stream>>>(x, xb);
    k_prep_w<<<192, 256, 0, stream>>>(w_init, w_conv, w_conv + HD * HD, Wt);

    int gemm_grid = (NN + 127) / 128;  // 782
    int agg_grid = (NN + 3) / 4;       // 25000

    // layer 1
    k_gemm_mfma<<<gemm_grid, 256, 0, stream>>>(xb, Wt, dinv, gbf);
    k_aggregate<<<agg_grid, 256, 0, stream>>>((const unsigned int*)gbf, row_start, col, dinv, b_init, (unsigned int*)hAbf);
    // layer 2
    k_gemm_mfma<<<gemm_grid, 256, 0, stream>>>(hAbf, Wt + 16384, dinv, gbf);
    k_aggregate<<<agg_grid, 256, 0, stream>>>((const unsigned int*)gbf, row_start, col, dinv, b_conv, (unsigned int*)hAbf);
    // layer 3
    k_gemm_mfma<<<gemm_grid, 256, 0, stream>>>(hAbf, Wt + 2 * 16384, dinv, gbf);
    k_aggregate<<<agg_grid, 256, 0, stream>>>((const unsigned int*)gbf, row_start, col, dinv, b_conv + HD, (unsigned int*)hAbf);

    k_pool<<<GG, 512, 0, stream>>>(hAbf, batch, pooled);
    k_head<<<GG, 128, 0, stream>>>(pooled, w_h1, b_h1, w_h2, b_h2, out);
}

// Round 5
// 517.285 us; speedup vs baseline: 1.7136x; 1.1123x over previous
//
#include <hip/hip_runtime.h>
#include <hip/hip_bf16.h>
#include <math.h>

#define NN 100000
#define EE 1600000
#define HD 128
#define GG 128
#define CC 10

#define BKSH 9                    // bucket = dst >> 9 (512 nodes/bucket)
#define NBK  196                  // ceil(100000/512)
#define CH   4096                 // edges per scatter chunk
#define MAXB 12288                // bucket capacity for LDS col staging (mean 8163, +45 sigma)

typedef __attribute__((ext_vector_type(8))) short short8;
typedef __attribute__((ext_vector_type(4))) float f32x4;

// bf16 helpers (RNE)
__device__ __forceinline__ unsigned short f2bf(float f) {
    union { float f; unsigned u; } a; a.f = f;
    unsigned r = a.u + 0x7fff + ((a.u >> 16) & 1);
    return (unsigned short)(r >> 16);
}
__device__ __forceinline__ float bflo(unsigned u) {
    union { unsigned u; float f; } a; a.u = u << 16; return a.f;
}
__device__ __forceinline__ float bfhi(unsigned u) {
    union { unsigned u; float f; } a; a.u = u & 0xffff0000u; return a.f;
}
__device__ __forceinline__ float bfu(unsigned short u) {
    union { unsigned u; float f; } a; a.u = ((unsigned)u) << 16; return a.f;
}

// ---------------- bucketed CSR build ----------------

// 1) histogram of dst>>9 into 196 buckets, LDS-privatized
__global__ __launch_bounds__(256) void k_bhist(const int* __restrict__ dst,
                                               unsigned* __restrict__ bucket_cnt) {
    __shared__ unsigned cnt[256];
    int t = threadIdx.x;
    cnt[t] = 0;
    __syncthreads();
    int base = blockIdx.x * CH;
#pragma unroll
    for (int k = 0; k < 16; ++k) {
        int e = base + k * 256 + t;
        if (e < EE) atomicAdd(&cnt[((unsigned)dst[e]) >> BKSH], 1u);
    }
    __syncthreads();
    if (cnt[t]) atomicAdd(&bucket_cnt[t], cnt[t]);
}

// 2) scan bucket counts -> bucket_start, init cursors, set row_start[NN]
__global__ void k_bscan(const unsigned* __restrict__ bucket_cnt,
                        unsigned* __restrict__ bucket_start,
                        unsigned* __restrict__ cursor, int* __restrict__ row_start) {
    __shared__ unsigned s[256];
    int t = threadIdx.x;
    unsigned v = bucket_cnt[t];
    s[t] = v;
    __syncthreads();
    for (int off = 1; off < 256; off <<= 1) {
        unsigned a = (t >= off) ? s[t - off] : 0;
        __syncthreads();
        s[t] += a;
        __syncthreads();
    }
    unsigned excl = s[t] - v;
    bucket_start[t] = excl;
    cursor[t] = excl;
    if (t == 255) bucket_start[256] = excl + v;  // == EE
    if (t == 0) row_start[NN] = EE;
}

// 3) scatter (src,dst) pairs into bucket regions with LDS staging (coalesced flushes)
__global__ __launch_bounds__(256) void k_bscatter(const int* __restrict__ src,
                                                  const int* __restrict__ dst,
                                                  unsigned* __restrict__ cursor,
                                                  uint2* __restrict__ ebuf) {
    __shared__ unsigned cnt[256], lst[256], gbase[256], ss[256];
    __shared__ uint2 stage[CH];
    __shared__ unsigned char binid[CH];
    int t = threadIdx.x;
    cnt[t] = 0;
    __syncthreads();
    int base = blockIdx.x * CH;
    int nvalid = EE - base; if (nvalid > CH) nvalid = CH;

    unsigned bk[16], rk[16];
    int sv[16], dv[16];
#pragma unroll
    for (int k = 0; k < 16; ++k) {
        int e = base + k * 256 + t;
        bk[k] = 0xffffffffu;
        if (e < EE) {
            int d = dst[e];
            sv[k] = src[e];
            dv[k] = d;
            unsigned b = ((unsigned)d) >> BKSH;
            bk[k] = b;
            rk[k] = atomicAdd(&cnt[b], 1u);
        }
    }
    __syncthreads();
    unsigned v = cnt[t];
    ss[t] = v;
    __syncthreads();
    for (int off = 1; off < 256; off <<= 1) {
        unsigned a = (t >= off) ? ss[t - off] : 0;
        __syncthreads();
        ss[t] += a;
        __syncthreads();
    }
    lst[t] = ss[t] - v;
    if (v) gbase[t] = atomicAdd(&cursor[t], v);
    __syncthreads();
#pragma unroll
    for (int k = 0; k < 16; ++k) {
        if (bk[k] != 0xffffffffu) {
            unsigned slot = lst[bk[k]] + rk[k];
            stage[slot] = make_uint2((unsigned)sv[k], (unsigned)dv[k]);
            binid[slot] = (unsigned char)bk[k];
        }
    }
    __syncthreads();
    for (int j = t; j < nvalid; j += 256) {
        unsigned b = binid[j];
        ebuf[gbase[b] + (j - lst[b])] = stage[j];
    }
}

// 4) per-bucket CSR: local deg/scan/col placement all in LDS; coalesced global writes only
__global__ __launch_bounds__(512) void k_bucket_csr(const uint2* __restrict__ ebuf,
                                                    const unsigned* __restrict__ bucket_start,
                                                    int* __restrict__ row_start,
                                                    float* __restrict__ dinv,
                                                    int* __restrict__ col) {
    __shared__ unsigned degl[512], lst[512], lfill[512], ss[512];
    __shared__ int colstage[MAXB];
    int t = threadIdx.x, b = blockIdx.x;
    unsigned ebase = bucket_start[b];
    int size = (int)(bucket_start[b + 1] - ebase);
    int nbase = b << BKSH;
    degl[t] = 0;
    lfill[t] = 0;
    __syncthreads();
    for (int j = t; j < size; j += 512)
        atomicAdd(&degl[ebuf[ebase + j].y - nbase], 1u);
    __syncthreads();
    unsigned v = degl[t];
    ss[t] = v;
    __syncthreads();
    for (int off = 1; off < 512; off <<= 1) {
        unsigned a = (t >= off) ? ss[t - off] : 0;
        __syncthreads();
        ss[t] += a;
        __syncthreads();
    }
    lst[t] = ss[t] - v;
    int node = nbase + t;
    if (node < NN) {
        row_start[node] = (int)(ebase + lst[t]);
        dinv[node] = rsqrtf((float)(v + 1));
    }
    __syncthreads();
    if (size <= MAXB) {
        for (int j = t; j < size; j += 512) {
            uint2 u = ebuf[ebase + j];
            unsigned l = u.y - nbase;
            unsigned pos = lst[l] + atomicAdd(&lfill[l], 1u);
            colstage[pos] = (int)u.x;
        }
        __syncthreads();
        for (int j = t; j < size; j += 512) col[ebase + j] = colstage[j];
    } else {  // statistically impossible fallback
        for (int j = t; j < size; j += 512) {
            uint2 u = ebuf[ebase + j];
            unsigned l = u.y - nbase;
            unsigned pos = lst[l] + atomicAdd(&lfill[l], 1u);
            col[ebase + pos] = (int)u.x;
        }
    }
}

// ---------------- prep: x -> bf16, W -> bf16 transposed ----------------

__global__ void k_cast_bf(const float* __restrict__ x, unsigned short* __restrict__ xb) {
    int i = blockIdx.x * 256 + threadIdx.x;  // one float4 per thread
    float4 v = ((const float4*)x)[i];
    ushort4 o;
    o.x = f2bf(v.x); o.y = f2bf(v.y); o.z = f2bf(v.z); o.w = f2bf(v.w);
    ((ushort4*)xb)[i] = o;
}

// Wt[mat][n][k] = bf16(W[mat][k][n])
__global__ void k_prep_w(const float* __restrict__ w0, const float* __restrict__ w1,
                         const float* __restrict__ w2, unsigned short* __restrict__ Wt) {
    int b = blockIdx.x;
    int mat = b >> 6;
    int idx = (b & 63) * 256 + threadIdx.x;
    int k = idx >> 7, n = idx & 127;
    const float* Wm = (mat == 0) ? w0 : ((mat == 1) ? w1 : w2);
    Wt[mat * 16384 + n * 128 + k] = f2bf(Wm[k * 128 + n]);
}

// ---------------- GEMM (MFMA bf16): gbf = bf16(dinv ⊙ (A @ W)) ----------------

#define LDK 136  // ushort stride

__global__ __launch_bounds__(256) void k_gemm_mfma(
    const unsigned short* __restrict__ A, const unsigned short* __restrict__ Wt,
    const float* __restrict__ dinv, unsigned short* __restrict__ out_bf) {
    __shared__ unsigned short As[128 * LDK];
    __shared__ unsigned short Ws[128 * LDK];
    __shared__ float dv[128];
    int t = threadIdx.x;
    int r0 = blockIdx.x * 128;

#pragma unroll
    for (int p = 0; p < 8; ++p) {
        int chunk = p * 256 + t;
        int row = chunk >> 4, kc = chunk & 15;
        uint4 v = make_uint4(0u, 0u, 0u, 0u);
        if (r0 + row < NN) v = *(const uint4*)(A + (size_t)(r0 + row) * HD + kc * 8);
        *(uint4*)(As + row * LDK + kc * 8) = v;
        uint4 w = *(const uint4*)(Wt + (size_t)row * HD + kc * 8);
        *(uint4*)(Ws + row * LDK + kc * 8) = w;
    }
    if (t < 128) dv[t] = (r0 + t < NN) ? dinv[r0 + t] : 0.f;
    __syncthreads();

    int wave = t >> 6, lane = t & 63, quad = lane >> 4, l16 = lane & 15;
    int wr = (wave >> 1) * 64, wc = (wave & 1) * 64;

    f32x4 acc[4][4];
#pragma unroll
    for (int i = 0; i < 4; ++i)
#pragma unroll
        for (int j = 0; j < 4; ++j) acc[i][j] = (f32x4){0.f, 0.f, 0.f, 0.f};

#pragma unroll
    for (int kk = 0; kk < 4; ++kk) {
        int k0 = kk * 32 + quad * 8;
        short8 af[4], bfr[4];
#pragma unroll
        for (int i = 0; i < 4; ++i)
            af[i] = *(const short8*)(As + (wr + i * 16 + l16) * LDK + k0);
#pragma unroll
        for (int j = 0; j < 4; ++j)
            bfr[j] = *(const short8*)(Ws + (wc + j * 16 + l16) * LDK + k0);
#pragma unroll
        for (int i = 0; i < 4; ++i)
#pragma unroll
            for (int j = 0; j < 4; ++j)
                acc[i][j] = __builtin_amdgcn_mfma_f32_16x16x32_bf16(af[i], bfr[j], acc[i][j], 0, 0, 0);
    }
    __syncthreads();

#pragma unroll
    for (int i = 0; i < 4; ++i) {
        int lr = wr + i * 16 + quad * 4;
#pragma unroll
        for (int reg = 0; reg < 4; ++reg) {
            float sc = dv[lr + reg];
#pragma unroll
            for (int j = 0; j < 4; ++j)
                As[(lr + reg) * LDK + wc + j * 16 + l16] = f2bf(acc[i][j][reg] * sc);
        }
    }
    __syncthreads();

    int row = t >> 1, half = t & 1;
    if (r0 + row < NN) {
        unsigned short* dp = out_bf + (size_t)(r0 + row) * HD + half * 64;
        const unsigned short* sp = As + row * LDK + half * 64;
#pragma unroll
        for (int q = 0; q < 8; ++q)
            *(uint4*)(dp + q * 8) = *(const uint4*)(sp + q * 8);
    }
}

// ---------------- aggregation ----------------

__global__ __launch_bounds__(256) void k_aggregate(
    const unsigned int* __restrict__ gbf, const int* __restrict__ row_start,
    const int* __restrict__ col, const float* __restrict__ dinv,
    const float* __restrict__ bias, unsigned int* __restrict__ out) {
    int node = blockIdx.x * 4 + (threadIdx.x >> 6);
    if (node >= NN) return;
    int lane = threadIdx.x & 63;
    unsigned int su = gbf[node * 64 + lane];  // self loop
    float ax = bflo(su), ay = bfhi(su);
    int e = row_start[node], end = row_start[node + 1];
    for (; e + 8 <= end; e += 8) {
        int s0 = col[e], s1 = col[e + 1], s2 = col[e + 2], s3 = col[e + 3];
        int s4 = col[e + 4], s5 = col[e + 5], s6 = col[e + 6], s7 = col[e + 7];
        unsigned int u0 = gbf[s0 * 64 + lane];
        unsigned int u1 = gbf[s1 * 64 + lane];
        unsigned int u2 = gbf[s2 * 64 + lane];
        unsigned int u3 = gbf[s3 * 64 + lane];
        unsigned int u4 = gbf[s4 * 64 + lane];
        unsigned int u5 = gbf[s5 * 64 + lane];
        unsigned int u6 = gbf[s6 * 64 + lane];
        unsigned int u7 = gbf[s7 * 64 + lane];
        ax += ((bflo(u0) + bflo(u1)) + (bflo(u2) + bflo(u3))) +
              ((bflo(u4) + bflo(u5)) + (bflo(u6) + bflo(u7)));
        ay += ((bfhi(u0) + bfhi(u1)) + (bfhi(u2) + bfhi(u3))) +
              ((bfhi(u4) + bfhi(u5)) + (bfhi(u6) + bfhi(u7)));
    }
    for (; e < end; ++e) {
        unsigned int u = gbf[col[e] * 64 + lane];
        ax += bflo(u);
        ay += bfhi(u);
    }
    float sc = dinv[node];
    float2 bb = ((const float2*)bias)[lane];
    float rx = fmaxf(fmaf(ax, sc, bb.x), 0.f);
    float ry = fmaxf(fmaf(ay, sc, bb.y), 0.f);
    out[node * 64 + lane] = (unsigned)f2bf(rx) | ((unsigned)f2bf(ry) << 16);
}

// ---------------- mean pool per graph (batch sorted), bf16 input ----------------

__device__ __forceinline__ int lower_bound_i(const int* a, int n, int key) {
    int lo = 0, hi = n;
    while (lo < hi) {
        int mid = (lo + hi) >> 1;
        if (a[mid] < key) lo = mid + 1;
        else hi = mid;
    }
    return lo;
}

__global__ __launch_bounds__(512) void k_pool(const unsigned short* __restrict__ h,
                                              const int* __restrict__ batch,
                                              float* __restrict__ pooled) {
    __shared__ float partial[4][HD];
    __shared__ int range[2];
    int t = threadIdx.x, g = blockIdx.x;
    if (t == 0) {
        range[0] = lower_bound_i(batch, NN, g);
        range[1] = lower_bound_i(batch, NN, g + 1);
    }
    __syncthreads();
    int lo = range[0], hi = range[1];
    int feat = t & 127, sl = t >> 7;
    float acc = 0.f;
    for (int r = lo + sl; r < hi; r += 4) acc += bfu(h[(size_t)r * HD + feat]);
    partial[sl][feat] = acc;
    __syncthreads();
    if (t < HD) {
        float s = partial[0][t] + partial[1][t] + partial[2][t] + partial[3][t];
        float cnt = (float)(hi - lo);
        pooled[g * HD + t] = s / fmaxf(cnt, 1.f);
    }
}

// ---------------- head ----------------

__global__ __launch_bounds__(128) void k_head(const float* __restrict__ pooled,
                                              const float* __restrict__ w1,
                                              const float* __restrict__ b1,
                                              const float* __restrict__ w2,
                                              const float* __restrict__ b2,
                                              float* __restrict__ out) {
    __shared__ float row[HD], hrow[HD], logits[CC];
    int g = blockIdx.x, t = threadIdx.x;
    row[t] = pooled[g * HD + t];
    __syncthreads();
    float acc = b1[t];
    for (int k = 0; k < HD; ++k) acc = fmaf(row[k], w1[k * HD + t], acc);
    hrow[t] = fmaxf(acc, 0.f);
    __syncthreads();
    if (t < CC) {
        float a = b2[t];
        for (int k = 0; k < HD; ++k) a = fmaf(hrow[k], w2[k * CC + t], a);
        logits[t] = a;
    }
    __syncthreads();
    if (t < CC) {
        float m = logits[0];
        for (int i = 1; i < CC; ++i) m = fmaxf(m, logits[i]);
        float s = 0.f;
        for (int i = 0; i < CC; ++i) s += expf(logits[i] - m);
        out[g * CC + t] = logits[t] - m - logf(s);
    }
}

// ---------------- launch ----------------

extern "C" void kernel_launch(void* const* d_in, const int* in_sizes, int n_in,
                              void* d_out, int out_size, void* d_ws, size_t ws_size,
                              hipStream_t stream) {
    const float* x      = (const float*)d_in[0];
    const int*   ei     = (const int*)d_in[1];   // [2,E]: row0=src, row1=dst
    const int*   batch  = (const int*)d_in[2];
    const float* w_init = (const float*)d_in[3];
    const float* b_init = (const float*)d_in[4];
    const float* w_conv = (const float*)d_in[5];  // [2,128,128]
    const float* b_conv = (const float*)d_in[6];  // [2,128]
    const float* w_h1   = (const float*)d_in[7];
    const float* b_h1   = (const float*)d_in[8];
    const float* w_h2   = (const float*)d_in[9];
    const float* b_h2   = (const float*)d_in[10];
    float* out = (float*)d_out;
    (void)n_in; (void)in_sizes; (void)out_size; (void)ws_size;

    char* ws = (char*)d_ws;
    size_t off = 0;
    auto alloc = [&](size_t bytes) -> void* {
        void* p = ws + off;
        off += (bytes + 255) & ~(size_t)255;
        return p;
    };
    unsigned short* hAbf         = (unsigned short*)alloc((size_t)NN * HD * 2);
    unsigned short* gbf          = (unsigned short*)alloc((size_t)NN * HD * 2);
    unsigned short* xb           = (unsigned short*)alloc((size_t)NN * HD * 2);
    unsigned short* Wt           = (unsigned short*)alloc(3 * 16384 * 2);
    float*          dinv         = (float*)alloc((size_t)NN * 4);
    int*            row_start    = (int*)alloc((size_t)(NN + 1) * 4);
    int*            col          = (int*)alloc((size_t)EE * 4);
    uint2*          ebuf         = (uint2*)alloc((size_t)EE * 8);
    unsigned*       bucket_cnt   = (unsigned*)alloc(256 * 4);
    unsigned*       bucket_start = (unsigned*)alloc(257 * 4);
    unsigned*       cursor       = (unsigned*)alloc(256 * 4);
    float*          pooled       = (float*)alloc((size_t)GG * HD * 4);

    const int* srcp = ei;
    const int* dstp = ei + EE;

    hipMemsetAsync(bucket_cnt, 0, 256 * 4, stream);

    int nchunks = (EE + CH - 1) / CH;  // 391
    k_bhist<<<nchunks, 256, 0, stream>>>(dstp, bucket_cnt);
    k_bscan<<<1, 256, 0, stream>>>(bucket_cnt, bucket_start, cursor, row_start);
    k_bscatter<<<nchunks, 256, 0, stream>>>(srcp, dstp, cursor, ebuf);
    k_bucket_csr<<<NBK, 512, 0, stream>>>(ebuf, bucket_start, row_start, dinv, col);

    k_cast_bf<<<(NN * HD / 4) / 256 + 1, 256, 0, stream>>>(x, xb);
    k_prep_w<<<192, 256, 0, stream>>>(w_init, w_conv, w_conv + HD * HD, Wt);

    int gemm_grid = (NN + 127) / 128;  // 782
    int agg_grid = (NN + 3) / 4;       // 25000

    // layer 1
    k_gemm_mfma<<<gemm_grid, 256, 0, stream>>>(xb, Wt, dinv, gbf);
    k_aggregate<<<agg_grid, 256, 0, stream>>>((const unsigned int*)gbf, row_start, col, dinv, b_init, (unsigned int*)hAbf);
    // layer 2
    k_gemm_mfma<<<gemm_grid, 256, 0, stream>>>(hAbf, Wt + 16384, dinv, gbf);
    k_aggregate<<<agg_grid, 256, 0, stream>>>((const unsigned int*)gbf, row_start, col, dinv, b_conv, (unsigned int*)hAbf);
    // layer 3
    k_gemm_mfma<<<gemm_grid, 256, 0, stream>>>(hAbf, Wt + 2 * 16384, dinv, gbf);
    k_aggregate<<<agg_grid, 256, 0, stream>>>((const unsigned int*)gbf, row_start, col, dinv, b_conv + HD, (unsigned int*)hAbf);

    k_pool<<<GG, 512, 0, stream>>>(hAbf, batch, pooled);
    k_head<<<GG, 128, 0, stream>>>(pooled, w_h1, b_h1, w_h2, b_h2, out);
}

// Round 6
// 405.643 us; speedup vs baseline: 2.1852x; 1.2752x over previous
//
#include <hip/hip_runtime.h>
#include <hip/hip_bf16.h>
#include <math.h>

#define NN 100000
#define EE 1600000
#define HD 128
#define GG 128
#define CC 10

#define BKSH 9                    // bucket = dst >> 9 (512 nodes/bucket)
#define NBK  196                  // ceil(100000/512)
#define CH   4096                 // edges per scatter chunk
#define MAXB 12288                // bucket capacity for LDS col staging

typedef __attribute__((ext_vector_type(8))) short short8;
typedef __attribute__((ext_vector_type(4))) float f32x4;
typedef __attribute__((ext_vector_type(2))) float f32x2;

// bf16 helpers (RNE)
__device__ __forceinline__ unsigned short f2bf(float f) {
    union { float f; unsigned u; } a; a.f = f;
    unsigned r = a.u + 0x7fff + ((a.u >> 16) & 1);
    return (unsigned short)(r >> 16);
}
__device__ __forceinline__ float bfu(unsigned short u) {
    union { unsigned u; float f; } a; a.u = ((unsigned)u) << 16; return a.f;
}

// fp8 e4m3 pack/unpack (HW cvt, 2 values/inst)
__device__ __forceinline__ unsigned pk4fp8(float f0, float f1, float f2, float f3) {
    unsigned u = 0;
    u = __builtin_amdgcn_cvt_pk_fp8_f32(f0, f1, u, false);
    u = __builtin_amdgcn_cvt_pk_fp8_f32(f2, f3, u, true);
    return u;
}

// ---------------- bucketed CSR build ----------------

__global__ __launch_bounds__(256) void k_bhist(const int* __restrict__ dst,
                                               unsigned* __restrict__ bucket_cnt) {
    __shared__ unsigned cnt[256];
    int t = threadIdx.x;
    cnt[t] = 0;
    __syncthreads();
    int base = blockIdx.x * CH;
#pragma unroll
    for (int k = 0; k < 16; ++k) {
        int e = base + k * 256 + t;
        if (e < EE) atomicAdd(&cnt[((unsigned)dst[e]) >> BKSH], 1u);
    }
    __syncthreads();
    if (cnt[t]) atomicAdd(&bucket_cnt[t], cnt[t]);
}

__global__ void k_bscan(const unsigned* __restrict__ bucket_cnt,
                        unsigned* __restrict__ bucket_start,
                        unsigned* __restrict__ cursor, int* __restrict__ row_start) {
    __shared__ unsigned s[256];
    int t = threadIdx.x;
    unsigned v = bucket_cnt[t];
    s[t] = v;
    __syncthreads();
    for (int off = 1; off < 256; off <<= 1) {
        unsigned a = (t >= off) ? s[t - off] : 0;
        __syncthreads();
        s[t] += a;
        __syncthreads();
    }
    unsigned excl = s[t] - v;
    bucket_start[t] = excl;
    cursor[t] = excl;
    if (t == 255) bucket_start[256] = excl + v;
    if (t == 0) row_start[NN] = EE;
}

// scatter packed (src<<9 | dst&511) into bucket regions, LDS-staged coalesced flush
__global__ __launch_bounds__(256) void k_bscatter(const int* __restrict__ src,
                                                  const int* __restrict__ dst,
                                                  unsigned* __restrict__ cursor,
                                                  unsigned* __restrict__ ebuf) {
    __shared__ unsigned cnt[256], lst[256], gbase[256], ss[256];
    __shared__ unsigned stage[CH];
    __shared__ unsigned char binid[CH];
    int t = threadIdx.x;
    cnt[t] = 0;
    __syncthreads();
    int base = blockIdx.x * CH;
    int nvalid = EE - base; if (nvalid > CH) nvalid = CH;

    unsigned bk[16], rk[16], pv[16];
#pragma unroll
    for (int k = 0; k < 16; ++k) {
        int e = base + k * 256 + t;
        bk[k] = 0xffffffffu;
        if (e < EE) {
            unsigned d = (unsigned)dst[e];
            unsigned b = d >> BKSH;
            pv[k] = (((unsigned)src[e]) << BKSH) | (d & ((1u << BKSH) - 1));
            bk[k] = b;
            rk[k] = atomicAdd(&cnt[b], 1u);
        }
    }
    __syncthreads();
    unsigned v = cnt[t];
    ss[t] = v;
    __syncthreads();
    for (int off = 1; off < 256; off <<= 1) {
        unsigned a = (t >= off) ? ss[t - off] : 0;
        __syncthreads();
        ss[t] += a;
        __syncthreads();
    }
    lst[t] = ss[t] - v;
    if (v) gbase[t] = atomicAdd(&cursor[t], v);
    __syncthreads();
#pragma unroll
    for (int k = 0; k < 16; ++k) {
        if (bk[k] != 0xffffffffu) {
            unsigned slot = lst[bk[k]] + rk[k];
            stage[slot] = pv[k];
            binid[slot] = (unsigned char)bk[k];
        }
    }
    __syncthreads();
    for (int j = t; j < nvalid; j += 256) {
        unsigned b = binid[j];
        ebuf[gbase[b] + (j - lst[b])] = stage[j];
    }
}

__global__ __launch_bounds__(512) void k_bucket_csr(const unsigned* __restrict__ ebuf,
                                                    const unsigned* __restrict__ bucket_start,
                                                    int* __restrict__ row_start,
                                                    float* __restrict__ dinv,
                                                    int* __restrict__ col) {
    __shared__ unsigned degl[512], lst[512], lfill[512], ss[512];
    __shared__ int colstage[MAXB];
    int t = threadIdx.x, b = blockIdx.x;
    unsigned ebase = bucket_start[b];
    int size = (int)(bucket_start[b + 1] - ebase);
    int nbase = b << BKSH;
    degl[t] = 0;
    lfill[t] = 0;
    __syncthreads();
    for (int j = t; j < size; j += 512)
        atomicAdd(&degl[ebuf[ebase + j] & 511u], 1u);
    __syncthreads();
    unsigned v = degl[t];
    ss[t] = v;
    __syncthreads();
    for (int off = 1; off < 512; off <<= 1) {
        unsigned a = (t >= off) ? ss[t - off] : 0;
        __syncthreads();
        ss[t] += a;
        __syncthreads();
    }
    lst[t] = ss[t] - v;
    int node = nbase + t;
    if (node < NN) {
        row_start[node] = (int)(ebase + lst[t]);
        dinv[node] = rsqrtf((float)(v + 1));
    }
    __syncthreads();
    if (size <= MAXB) {
        for (int j = t; j < size; j += 512) {
            unsigned u = ebuf[ebase + j];
            unsigned l = u & 511u;
            unsigned pos = lst[l] + atomicAdd(&lfill[l], 1u);
            colstage[pos] = (int)(u >> BKSH);
        }
        __syncthreads();
        for (int j = t; j < size; j += 512) col[ebase + j] = colstage[j];
    } else {
        for (int j = t; j < size; j += 512) {
            unsigned u = ebuf[ebase + j];
            unsigned l = u & 511u;
            unsigned pos = lst[l] + atomicAdd(&lfill[l], 1u);
            col[ebase + pos] = (int)(u >> BKSH);
        }
    }
}

// ---------------- W prep: Wt[mat][n][k] = bf16(W[mat][k][n]) ----------------

__global__ void k_prep_w(const float* __restrict__ w0, const float* __restrict__ w1,
                         const float* __restrict__ w2, unsigned short* __restrict__ Wt) {
    int b = blockIdx.x;
    int mat = b >> 6;
    int idx = (b & 63) * 256 + threadIdx.x;
    int k = idx >> 7, n = idx & 127;
    const float* Wm = (mat == 0) ? w0 : ((mat == 1) ? w1 : w2);
    Wt[mat * 16384 + n * 128 + k] = f2bf(Wm[k * 128 + n]);
}

// ---------------- GEMM (MFMA bf16): g8 = fp8(dinv ⊙ (A @ W)) ----------------
// A: f32 (layer 1) or bf16 (layers 2-3). 128x128 tile/block, 4 waves,
// each wave a 64x64 quadrant of 16x16x32 MFMA tiles. Epilogue packs fp8.

#define LDK 136  // ushort stride

template <bool F32IN>
__global__ __launch_bounds__(256) void k_gemm_mfma(
    const void* __restrict__ Ap, const unsigned short* __restrict__ Wt,
    const float* __restrict__ dinv, unsigned* __restrict__ g8) {
    __shared__ unsigned short As[128 * LDK];  // A tile [row][k]; reused as C tile
    __shared__ unsigned short Ws[128 * LDK];  // Wt tile [n][k]
    __shared__ float dv[128];
    int t = threadIdx.x;
    int r0 = blockIdx.x * 128;

#pragma unroll
    for (int p = 0; p < 8; ++p) {
        int chunk = p * 256 + t;
        int row = chunk >> 4, kc = chunk & 15;  // kc: group of 8 features
        uint4 sv = make_uint4(0u, 0u, 0u, 0u);
        if (F32IN) {
            const float* A = (const float*)Ap;
            if (r0 + row < NN) {
                const float* ap = A + (size_t)(r0 + row) * HD + kc * 8;
                float4 va = *(const float4*)ap;
                float4 vb = *(const float4*)(ap + 4);
                sv.x = (unsigned)f2bf(va.x) | ((unsigned)f2bf(va.y) << 16);
                sv.y = (unsigned)f2bf(va.z) | ((unsigned)f2bf(va.w) << 16);
                sv.z = (unsigned)f2bf(vb.x) | ((unsigned)f2bf(vb.y) << 16);
                sv.w = (unsigned)f2bf(vb.z) | ((unsigned)f2bf(vb.w) << 16);
            }
        } else {
            const unsigned short* A = (const unsigned short*)Ap;
            if (r0 + row < NN) sv = *(const uint4*)(A + (size_t)(r0 + row) * HD + kc * 8);
        }
        *(uint4*)(As + row * LDK + kc * 8) = sv;
        uint4 w = *(const uint4*)(Wt + (size_t)row * HD + kc * 8);
        *(uint4*)(Ws + row * LDK + kc * 8) = w;
    }
    if (t < 128) dv[t] = (r0 + t < NN) ? dinv[r0 + t] : 0.f;
    __syncthreads();

    int wave = t >> 6, lane = t & 63, quad = lane >> 4, l16 = lane & 15;
    int wr = (wave >> 1) * 64, wc = (wave & 1) * 64;

    f32x4 acc[4][4];
#pragma unroll
    for (int i = 0; i < 4; ++i)
#pragma unroll
        for (int j = 0; j < 4; ++j) acc[i][j] = (f32x4){0.f, 0.f, 0.f, 0.f};

#pragma unroll
    for (int kk = 0; kk < 4; ++kk) {
        int k0 = kk * 32 + quad * 8;
        short8 af[4], bfr[4];
#pragma unroll
        for (int i = 0; i < 4; ++i)
            af[i] = *(const short8*)(As + (wr + i * 16 + l16) * LDK + k0);
#pragma unroll
        for (int j = 0; j < 4; ++j)
            bfr[j] = *(const short8*)(Ws + (wc + j * 16 + l16) * LDK + k0);
#pragma unroll
        for (int i = 0; i < 4; ++i)
#pragma unroll
            for (int j = 0; j < 4; ++j)
                acc[i][j] = __builtin_amdgcn_mfma_f32_16x16x32_bf16(af[i], bfr[j], acc[i][j], 0, 0, 0);
    }
    __syncthreads();

    // C tile (bf16) into As, scaled by dinv
#pragma unroll
    for (int i = 0; i < 4; ++i) {
        int lr = wr + i * 16 + quad * 4;
#pragma unroll
        for (int reg = 0; reg < 4; ++reg) {
            float sc = dv[lr + reg];
#pragma unroll
            for (int j = 0; j < 4; ++j)
                As[(lr + reg) * LDK + wc + j * 16 + l16] = f2bf(acc[i][j][reg] * sc);
        }
    }
    __syncthreads();

    // pack fp8 and store: each thread one half-row (64 feats -> 16 uints)
    int row = t >> 1, half = t & 1;
    if (r0 + row < NN) {
        const unsigned short* sp = As + row * LDK + half * 64;
        unsigned og[16];
#pragma unroll
        for (int q = 0; q < 16; ++q)
            og[q] = pk4fp8(bfu(sp[4 * q]), bfu(sp[4 * q + 1]),
                           bfu(sp[4 * q + 2]), bfu(sp[4 * q + 3]));
        uint4* dp = (uint4*)(g8 + (size_t)(r0 + row) * 32 + half * 16);
#pragma unroll
        for (int q = 0; q < 4; ++q)
            dp[q] = make_uint4(og[4 * q], og[4 * q + 1], og[4 * q + 2], og[4 * q + 3]);
    }
}

// ---------------- aggregation: hA = bf16(relu(dinv[d]*(g[d]+sum g[s]) + b)) ----------------
// fp8 messages: row = 128B = 32 uints; half-wave (32 lanes) per node, 2 nodes/wave.

__global__ __launch_bounds__(256) void k_aggregate(
    const unsigned* __restrict__ g8, const int* __restrict__ row_start,
    const int* __restrict__ col, const float* __restrict__ dinv,
    const float* __restrict__ bias, uint2* __restrict__ out) {
    int node = blockIdx.x * 8 + (threadIdx.x >> 5);  // grid*8 == NN exactly
    int l = threadIdx.x & 31;
    unsigned su = g8[node * 32 + l];  // self loop
    f32x2 slo = __builtin_amdgcn_cvt_pk_f32_fp8(su, false);
    f32x2 shi = __builtin_amdgcn_cvt_pk_f32_fp8(su, true);
    float a0 = slo.x, a1 = slo.y, a2 = shi.x, a3 = shi.y;
    int e = row_start[node], end = row_start[node + 1];
    for (; e + 8 <= end; e += 8) {
        int s0 = col[e], s1 = col[e + 1], s2 = col[e + 2], s3 = col[e + 3];
        int s4 = col[e + 4], s5 = col[e + 5], s6 = col[e + 6], s7 = col[e + 7];
        unsigned u0 = g8[s0 * 32 + l];
        unsigned u1 = g8[s1 * 32 + l];
        unsigned u2 = g8[s2 * 32 + l];
        unsigned u3 = g8[s3 * 32 + l];
        unsigned u4 = g8[s4 * 32 + l];
        unsigned u5 = g8[s5 * 32 + l];
        unsigned u6 = g8[s6 * 32 + l];
        unsigned u7 = g8[s7 * 32 + l];
#pragma unroll
        for (int k = 0; k < 8; ++k) {
            unsigned u = (k == 0) ? u0 : (k == 1) ? u1 : (k == 2) ? u2 : (k == 3) ? u3
                       : (k == 4) ? u4 : (k == 5) ? u5 : (k == 6) ? u6 : u7;
            f32x2 lo = __builtin_amdgcn_cvt_pk_f32_fp8(u, false);
            f32x2 hi = __builtin_amdgcn_cvt_pk_f32_fp8(u, true);
            a0 += lo.x; a1 += lo.y; a2 += hi.x; a3 += hi.y;
        }
    }
    for (; e < end; ++e) {
        unsigned u = g8[col[e] * 32 + l];
        f32x2 lo = __builtin_amdgcn_cvt_pk_f32_fp8(u, false);
        f32x2 hi = __builtin_amdgcn_cvt_pk_f32_fp8(u, true);
        a0 += lo.x; a1 += lo.y; a2 += hi.x; a3 += hi.y;
    }
    float sc = dinv[node];
    float4 bb = ((const float4*)bias)[l];
    float r0 = fmaxf(fmaf(a0, sc, bb.x), 0.f);
    float r1 = fmaxf(fmaf(a1, sc, bb.y), 0.f);
    float r2 = fmaxf(fmaf(a2, sc, bb.z), 0.f);
    float r3 = fmaxf(fmaf(a3, sc, bb.w), 0.f);
    uint2 o;
    o.x = (unsigned)f2bf(r0) | ((unsigned)f2bf(r1) << 16);
    o.y = (unsigned)f2bf(r2) | ((unsigned)f2bf(r3) << 16);
    out[node * 32 + l] = o;
}

// ---------------- fused mean-pool + head ----------------

__device__ __forceinline__ int lower_bound_i(const int* a, int n, int key) {
    int lo = 0, hi = n;
    while (lo < hi) {
        int mid = (lo + hi) >> 1;
        if (a[mid] < key) lo = mid + 1;
        else hi = mid;
    }
    return lo;
}

__global__ __launch_bounds__(512) void k_poolhead(
    const unsigned short* __restrict__ h, const int* __restrict__ batch,
    const float* __restrict__ w1, const float* __restrict__ b1,
    const float* __restrict__ w2, const float* __restrict__ b2,
    float* __restrict__ out) {
    __shared__ float partial[4][HD];
    __shared__ float pooled[HD], hrow[HD], logits[CC];
    __shared__ int range[2];
    int t = threadIdx.x, g = blockIdx.x;
    if (t == 0) {
        range[0] = lower_bound_i(batch, NN, g);
        range[1] = lower_bound_i(batch, NN, g + 1);
    }
    __syncthreads();
    int lo = range[0], hi = range[1];
    int feat = t & 127, sl = t >> 7;
    float acc = 0.f;
    for (int r = lo + sl; r < hi; r += 4) acc += bfu(h[(size_t)r * HD + feat]);
    partial[sl][feat] = acc;
    __syncthreads();
    if (t < HD) {
        float s = partial[0][t] + partial[1][t] + partial[2][t] + partial[3][t];
        pooled[t] = s / fmaxf((float)(hi - lo), 1.f);
    }
    __syncthreads();
    if (t < HD) {
        float a = b1[t];
        for (int k = 0; k < HD; ++k) a = fmaf(pooled[k], w1[k * HD + t], a);
        hrow[t] = fmaxf(a, 0.f);
    }
    __syncthreads();
    if (t < CC) {
        float a = b2[t];
        for (int k = 0; k < HD; ++k) a = fmaf(hrow[k], w2[k * CC + t], a);
        logits[t] = a;
    }
    __syncthreads();
    if (t < CC) {
        float m = logits[0];
        for (int i = 1; i < CC; ++i) m = fmaxf(m, logits[i]);
        float s = 0.f;
        for (int i = 0; i < CC; ++i) s += expf(logits[i] - m);
        out[g * CC + t] = logits[t] - m - logf(s);
    }
}

// ---------------- launch ----------------

extern "C" void kernel_launch(void* const* d_in, const int* in_sizes, int n_in,
                              void* d_out, int out_size, void* d_ws, size_t ws_size,
                              hipStream_t stream) {
    const float* x      = (const float*)d_in[0];
    const int*   ei     = (const int*)d_in[1];   // [2,E]: row0=src, row1=dst
    const int*   batch  = (const int*)d_in[2];
    const float* w_init = (const float*)d_in[3];
    const float* b_init = (const float*)d_in[4];
    const float* w_conv = (const float*)d_in[5];  // [2,128,128]
    const float* b_conv = (const float*)d_in[6];  // [2,128]
    const float* w_h1   = (const float*)d_in[7];
    const float* b_h1   = (const float*)d_in[8];
    const float* w_h2   = (const float*)d_in[9];
    const float* b_h2   = (const float*)d_in[10];
    float* out = (float*)d_out;
    (void)n_in; (void)in_sizes; (void)out_size; (void)ws_size;

    char* ws = (char*)d_ws;
    size_t off = 0;
    auto alloc = [&](size_t bytes) -> void* {
        void* p = ws + off;
        off += (bytes + 255) & ~(size_t)255;
        return p;
    };
    unsigned short* hAbf         = (unsigned short*)alloc((size_t)NN * HD * 2);  // bf16 node state
    unsigned*       g8           = (unsigned*)alloc((size_t)NN * 32 * 4);        // fp8 messages 12.8MB
    unsigned short* Wt           = (unsigned short*)alloc(3 * 16384 * 2);
    float*          dinv         = (float*)alloc((size_t)NN * 4);
    int*            row_start    = (int*)alloc((size_t)(NN + 1) * 4);
    int*            col          = (int*)alloc((size_t)EE * 4);
    unsigned*       ebuf         = (unsigned*)alloc((size_t)EE * 4);             // packed 6.4MB
    unsigned*       bucket_cnt   = (unsigned*)alloc(256 * 4);
    unsigned*       bucket_start = (unsigned*)alloc(257 * 4);
    unsigned*       cursor       = (unsigned*)alloc(256 * 4);

    const int* srcp = ei;
    const int* dstp = ei + EE;

    hipMemsetAsync(bucket_cnt, 0, 256 * 4, stream);

    int nchunks = (EE + CH - 1) / CH;  // 391
    k_bhist<<<nchunks, 256, 0, stream>>>(dstp, bucket_cnt);
    k_bscan<<<1, 256, 0, stream>>>(bucket_cnt, bucket_start, cursor, row_start);
    k_bscatter<<<nchunks, 256, 0, stream>>>(srcp, dstp, cursor, ebuf);
    k_bucket_csr<<<NBK, 512, 0, stream>>>(ebuf, bucket_start, row_start, dinv, col);

    k_prep_w<<<192, 256, 0, stream>>>(w_init, w_conv, w_conv + HD * HD, Wt);

    int gemm_grid = (NN + 127) / 128;  // 782
    int agg_grid = NN / 8;             // 12500 (exact)

    // layer 1 (f32 input)
    k_gemm_mfma<true><<<gemm_grid, 256, 0, stream>>>(x, Wt, dinv, g8);
    k_aggregate<<<agg_grid, 256, 0, stream>>>(g8, row_start, col, dinv, b_init, (uint2*)hAbf);
    // layer 2
    k_gemm_mfma<false><<<gemm_grid, 256, 0, stream>>>(hAbf, Wt + 16384, dinv, g8);
    k_aggregate<<<agg_grid, 256, 0, stream>>>(g8, row_start, col, dinv, b_conv, (uint2*)hAbf);
    // layer 3
    k_gemm_mfma<false><<<gemm_grid, 256, 0, stream>>>(hAbf, Wt + 2 * 16384, dinv, g8);
    k_aggregate<<<agg_grid, 256, 0, stream>>>(g8, row_start, col, dinv, b_conv + HD, (uint2*)hAbf);

    k_poolhead<<<GG, 512, 0, stream>>>(hAbf, batch, w_h1, b_h1, w_h2, b_h2, out);
}

// Round 7
// 379.510 us; speedup vs baseline: 2.3357x; 1.0689x over previous
//
#include <hip/hip_runtime.h>
#include <hip/hip_bf16.h>
#include <math.h>

#define NN 100000
#define EE 1600000
#define HD 128
#define GG 128
#define CC 10

#define BKSH 9                    // bucket = dst >> 9 (512 nodes/bucket)
#define NBK  196                  // ceil(100000/512)
#define CH   4096                 // edges per scatter chunk
#define MAXB 12288                // bucket capacity for LDS col staging

typedef __attribute__((ext_vector_type(8))) short short8;
typedef __attribute__((ext_vector_type(4))) float f32x4;
typedef __attribute__((ext_vector_type(2))) float f32x2;

// bf16 helpers (RNE)
__device__ __forceinline__ unsigned short f2bf(float f) {
    union { float f; unsigned u; } a; a.f = f;
    unsigned r = a.u + 0x7fff + ((a.u >> 16) & 1);
    return (unsigned short)(r >> 16);
}
__device__ __forceinline__ float bfu(unsigned short u) {
    union { unsigned u; float f; } a; a.u = ((unsigned)u) << 16; return a.f;
}

// fp8 e4m3 pack (HW cvt, 2 values/inst)
__device__ __forceinline__ unsigned pk4fp8(float f0, float f1, float f2, float f3) {
    unsigned u = 0;
    u = __builtin_amdgcn_cvt_pk_fp8_f32(f0, f1, u, false);
    u = __builtin_amdgcn_cvt_pk_fp8_f32(f2, f3, u, true);
    return u;
}

// ---------------- bucketed CSR build ----------------

__global__ __launch_bounds__(256) void k_bhist(const int* __restrict__ dst,
                                               unsigned* __restrict__ bucket_cnt) {
    __shared__ unsigned cnt[256];
    int t = threadIdx.x;
    cnt[t] = 0;
    __syncthreads();
    int base = blockIdx.x * CH;
#pragma unroll
    for (int k = 0; k < 16; ++k) {
        int e = base + k * 256 + t;
        if (e < EE) atomicAdd(&cnt[((unsigned)dst[e]) >> BKSH], 1u);
    }
    __syncthreads();
    if (cnt[t]) atomicAdd(&bucket_cnt[t], cnt[t]);
}

__global__ void k_bscan(const unsigned* __restrict__ bucket_cnt,
                        unsigned* __restrict__ bucket_start,
                        unsigned* __restrict__ cursor, int* __restrict__ row_start) {
    __shared__ unsigned s[256];
    int t = threadIdx.x;
    unsigned v = bucket_cnt[t];
    s[t] = v;
    __syncthreads();
    for (int off = 1; off < 256; off <<= 1) {
        unsigned a = (t >= off) ? s[t - off] : 0;
        __syncthreads();
        s[t] += a;
        __syncthreads();
    }
    unsigned excl = s[t] - v;
    bucket_start[t] = excl;
    cursor[t] = excl;
    if (t == 255) bucket_start[256] = excl + v;
    if (t == 0) row_start[NN] = EE;
}

// scatter packed (src<<9 | dst&511) into bucket regions, LDS-staged coalesced flush
__global__ __launch_bounds__(256) void k_bscatter(const int* __restrict__ src,
                                                  const int* __restrict__ dst,
                                                  unsigned* __restrict__ cursor,
                                                  unsigned* __restrict__ ebuf) {
    __shared__ unsigned cnt[256], lst[256], gbase[256], ss[256];
    __shared__ unsigned stage[CH];
    __shared__ unsigned char binid[CH];
    int t = threadIdx.x;
    cnt[t] = 0;
    __syncthreads();
    int base = blockIdx.x * CH;
    int nvalid = EE - base; if (nvalid > CH) nvalid = CH;

    unsigned bk[16], rk[16], pv[16];
#pragma unroll
    for (int k = 0; k < 16; ++k) {
        int e = base + k * 256 + t;
        bk[k] = 0xffffffffu;
        if (e < EE) {
            unsigned d = (unsigned)dst[e];
            unsigned b = d >> BKSH;
            pv[k] = (((unsigned)src[e]) << BKSH) | (d & ((1u << BKSH) - 1));
            bk[k] = b;
            rk[k] = atomicAdd(&cnt[b], 1u);
        }
    }
    __syncthreads();
    unsigned v = cnt[t];
    ss[t] = v;
    __syncthreads();
    for (int off = 1; off < 256; off <<= 1) {
        unsigned a = (t >= off) ? ss[t - off] : 0;
        __syncthreads();
        ss[t] += a;
        __syncthreads();
    }
    lst[t] = ss[t] - v;
    if (v) gbase[t] = atomicAdd(&cursor[t], v);
    __syncthreads();
#pragma unroll
    for (int k = 0; k < 16; ++k) {
        if (bk[k] != 0xffffffffu) {
            unsigned slot = lst[bk[k]] + rk[k];
            stage[slot] = pv[k];
            binid[slot] = (unsigned char)bk[k];
        }
    }
    __syncthreads();
    for (int j = t; j < nvalid; j += 256) {
        unsigned b = binid[j];
        ebuf[gbase[b] + (j - lst[b])] = stage[j];
    }
}

__global__ __launch_bounds__(512) void k_bucket_csr(const unsigned* __restrict__ ebuf,
                                                    const unsigned* __restrict__ bucket_start,
                                                    int* __restrict__ row_start,
                                                    float* __restrict__ dinv,
                                                    int* __restrict__ col) {
    __shared__ unsigned degl[512], lst[512], lfill[512], ss[512];
    __shared__ int colstage[MAXB];
    int t = threadIdx.x, b = blockIdx.x;
    unsigned ebase = bucket_start[b];
    int size = (int)(bucket_start[b + 1] - ebase);
    int nbase = b << BKSH;
    degl[t] = 0;
    lfill[t] = 0;
    __syncthreads();
    for (int j = t; j < size; j += 512)
        atomicAdd(&degl[ebuf[ebase + j] & 511u], 1u);
    __syncthreads();
    unsigned v = degl[t];
    ss[t] = v;
    __syncthreads();
    for (int off = 1; off < 512; off <<= 1) {
        unsigned a = (t >= off) ? ss[t - off] : 0;
        __syncthreads();
        ss[t] += a;
        __syncthreads();
    }
    lst[t] = ss[t] - v;
    int node = nbase + t;
    if (node < NN) {
        row_start[node] = (int)(ebase + lst[t]);
        dinv[node] = rsqrtf((float)(v + 1));
    }
    __syncthreads();
    if (size <= MAXB) {
        for (int j = t; j < size; j += 512) {
            unsigned u = ebuf[ebase + j];
            unsigned l = u & 511u;
            unsigned pos = lst[l] + atomicAdd(&lfill[l], 1u);
            colstage[pos] = (int)(u >> BKSH);
        }
        __syncthreads();
        for (int j = t; j < size; j += 512) col[ebase + j] = colstage[j];
    } else {
        for (int j = t; j < size; j += 512) {
            unsigned u = ebuf[ebase + j];
            unsigned l = u & 511u;
            unsigned pos = lst[l] + atomicAdd(&lfill[l], 1u);
            col[ebase + pos] = (int)(u >> BKSH);
        }
    }
}

// ---------------- W prep: Wt[mat][n][k] = bf16(W[mat][k][n]) ----------------

__global__ void k_prep_w(const float* __restrict__ w0, const float* __restrict__ w1,
                         const float* __restrict__ w2, unsigned short* __restrict__ Wt) {
    int b = blockIdx.x;
    int mat = b >> 6;
    int idx = (b & 63) * 256 + threadIdx.x;
    int k = idx >> 7, n = idx & 127;
    const float* Wm = (mat == 0) ? w0 : ((mat == 1) ? w1 : w2);
    Wt[mat * 16384 + n * 128 + k] = f2bf(Wm[k * 128 + n]);
}

// ---------------- GEMM (MFMA bf16): g8 = fp8(dinv ⊙ (A @ W)) ----------------

#define LDK 136  // ushort stride

template <bool F32IN>
__global__ __launch_bounds__(256) void k_gemm_mfma(
    const void* __restrict__ Ap, const unsigned short* __restrict__ Wt,
    const float* __restrict__ dinv, unsigned* __restrict__ g8) {
    __shared__ unsigned short As[128 * LDK];  // A tile [row][k]; reused as C tile
    __shared__ unsigned short Ws[128 * LDK];  // Wt tile [n][k]
    __shared__ float dv[128];
    int t = threadIdx.x;
    int r0 = blockIdx.x * 128;

#pragma unroll
    for (int p = 0; p < 8; ++p) {
        int chunk = p * 256 + t;
        int row = chunk >> 4, kc = chunk & 15;
        uint4 sv = make_uint4(0u, 0u, 0u, 0u);
        if (F32IN) {
            const float* A = (const float*)Ap;
            if (r0 + row < NN) {
                const float* ap = A + (size_t)(r0 + row) * HD + kc * 8;
                float4 va = *(const float4*)ap;
                float4 vb = *(const float4*)(ap + 4);
                sv.x = (unsigned)f2bf(va.x) | ((unsigned)f2bf(va.y) << 16);
                sv.y = (unsigned)f2bf(va.z) | ((unsigned)f2bf(va.w) << 16);
                sv.z = (unsigned)f2bf(vb.x) | ((unsigned)f2bf(vb.y) << 16);
                sv.w = (unsigned)f2bf(vb.z) | ((unsigned)f2bf(vb.w) << 16);
            }
        } else {
            const unsigned short* A = (const unsigned short*)Ap;
            if (r0 + row < NN) sv = *(const uint4*)(A + (size_t)(r0 + row) * HD + kc * 8);
        }
        *(uint4*)(As + row * LDK + kc * 8) = sv;
        uint4 w = *(const uint4*)(Wt + (size_t)row * HD + kc * 8);
        *(uint4*)(Ws + row * LDK + kc * 8) = w;
    }
    if (t < 128) dv[t] = (r0 + t < NN) ? dinv[r0 + t] : 0.f;
    __syncthreads();

    int wave = t >> 6, lane = t & 63, quad = lane >> 4, l16 = lane & 15;
    int wr = (wave >> 1) * 64, wc = (wave & 1) * 64;

    f32x4 acc[4][4];
#pragma unroll
    for (int i = 0; i < 4; ++i)
#pragma unroll
        for (int j = 0; j < 4; ++j) acc[i][j] = (f32x4){0.f, 0.f, 0.f, 0.f};

#pragma unroll
    for (int kk = 0; kk < 4; ++kk) {
        int k0 = kk * 32 + quad * 8;
        short8 af[4], bfr[4];
#pragma unroll
        for (int i = 0; i < 4; ++i)
            af[i] = *(const short8*)(As + (wr + i * 16 + l16) * LDK + k0);
#pragma unroll
        for (int j = 0; j < 4; ++j)
            bfr[j] = *(const short8*)(Ws + (wc + j * 16 + l16) * LDK + k0);
#pragma unroll
        for (int i = 0; i < 4; ++i)
#pragma unroll
            for (int j = 0; j < 4; ++j)
                acc[i][j] = __builtin_amdgcn_mfma_f32_16x16x32_bf16(af[i], bfr[j], acc[i][j], 0, 0, 0);
    }
    __syncthreads();

#pragma unroll
    for (int i = 0; i < 4; ++i) {
        int lr = wr + i * 16 + quad * 4;
#pragma unroll
        for (int reg = 0; reg < 4; ++reg) {
            float sc = dv[lr + reg];
#pragma unroll
            for (int j = 0; j < 4; ++j)
                As[(lr + reg) * LDK + wc + j * 16 + l16] = f2bf(acc[i][j][reg] * sc);
        }
    }
    __syncthreads();

    int row = t >> 1, half = t & 1;
    if (r0 + row < NN) {
        const unsigned short* sp = As + row * LDK + half * 64;
        unsigned og[16];
#pragma unroll
        for (int q = 0; q < 16; ++q)
            og[q] = pk4fp8(bfu(sp[4 * q]), bfu(sp[4 * q + 1]),
                           bfu(sp[4 * q + 2]), bfu(sp[4 * q + 3]));
        uint4* dp = (uint4*)(g8 + (size_t)(r0 + row) * 32 + half * 16);
#pragma unroll
        for (int q = 0; q < 4; ++q)
            dp[q] = make_uint4(og[4 * q], og[4 * q + 1], og[4 * q + 2], og[4 * q + 3]);
    }
}

// ---------------- aggregation: hA = bf16(relu(dinv[d]*(g[d]+sum g[s]) + b)) ----------------
// fp8 messages: row = 128B = 32 uints; half-wave (32 lanes) per node.

__global__ __launch_bounds__(256) void k_aggregate(
    const unsigned* __restrict__ g8, const int* __restrict__ row_start,
    const int* __restrict__ col, const float* __restrict__ dinv,
    const float* __restrict__ bias, uint2* __restrict__ out) {
    int node = blockIdx.x * 8 + (threadIdx.x >> 5);  // grid*8 == NN exactly
    int l = threadIdx.x & 31;
    unsigned su = g8[node * 32 + l];  // self loop
    f32x2 slo = __builtin_amdgcn_cvt_pk_f32_fp8(su, false);
    f32x2 shi = __builtin_amdgcn_cvt_pk_f32_fp8(su, true);
    float a0 = slo.x, a1 = slo.y, a2 = shi.x, a3 = shi.y;
    int e = row_start[node], end = row_start[node + 1];
    for (; e + 8 <= end; e += 8) {
        int s0 = col[e], s1 = col[e + 1], s2 = col[e + 2], s3 = col[e + 3];
        int s4 = col[e + 4], s5 = col[e + 5], s6 = col[e + 6], s7 = col[e + 7];
        unsigned u0 = g8[s0 * 32 + l];
        unsigned u1 = g8[s1 * 32 + l];
        unsigned u2 = g8[s2 * 32 + l];
        unsigned u3 = g8[s3 * 32 + l];
        unsigned u4 = g8[s4 * 32 + l];
        unsigned u5 = g8[s5 * 32 + l];
        unsigned u6 = g8[s6 * 32 + l];
        unsigned u7 = g8[s7 * 32 + l];
#pragma unroll
        for (int k = 0; k < 8; ++k) {
            unsigned u = (k == 0) ? u0 : (k == 1) ? u1 : (k == 2) ? u2 : (k == 3) ? u3
                       : (k == 4) ? u4 : (k == 5) ? u5 : (k == 6) ? u6 : u7;
            f32x2 lo = __builtin_amdgcn_cvt_pk_f32_fp8(u, false);
            f32x2 hi = __builtin_amdgcn_cvt_pk_f32_fp8(u, true);
            a0 += lo.x; a1 += lo.y; a2 += hi.x; a3 += hi.y;
        }
    }
    for (; e < end; ++e) {
        unsigned u = g8[col[e] * 32 + l];
        f32x2 lo = __builtin_amdgcn_cvt_pk_f32_fp8(u, false);
        f32x2 hi = __builtin_amdgcn_cvt_pk_f32_fp8(u, true);
        a0 += lo.x; a1 += lo.y; a2 += hi.x; a3 += hi.y;
    }
    float sc = dinv[node];
    float4 bb = ((const float4*)bias)[l];
    float r0 = fmaxf(fmaf(a0, sc, bb.x), 0.f);
    float r1 = fmaxf(fmaf(a1, sc, bb.y), 0.f);
    float r2 = fmaxf(fmaf(a2, sc, bb.z), 0.f);
    float r3 = fmaxf(fmaf(a3, sc, bb.w), 0.f);
    uint2 o;
    o.x = (unsigned)f2bf(r0) | ((unsigned)f2bf(r1) << 16);
    o.y = (unsigned)f2bf(r2) | ((unsigned)f2bf(r3) << 16);
    out[node * 32 + l] = o;
}

// ---------------- parallel mean-pool: partial sums via f32 atomics ----------------
// 782 blocks x 256 threads = 2 row-slots x 128 feats; batch sorted -> register runs.

__global__ __launch_bounds__(256) void k_pool_partial(
    const unsigned short* __restrict__ h, const int* __restrict__ batch,
    float* __restrict__ pooled, float* __restrict__ cntg) {
    int t = threadIdx.x;
    int slot = t >> 7, feat = t & 127;
    int base = blockIdx.x * 128;
    int endr = base + 128; if (endr > NN) endr = NN;
    float acc = 0.f;
    int cur = -1, run = 0;
    for (int r = base + slot; r < endr; r += 2) {
        int g = batch[r];  // wave-uniform -> scalar load
        float v = bfu(h[(size_t)r * HD + feat]);
        if (g != cur) {
            if (cur >= 0) {
                atomicAdd(&pooled[cur * HD + feat], acc);
                if (feat == 0) atomicAdd(&cntg[cur], (float)run);
            }
            cur = g; acc = 0.f; run = 0;
        }
        acc += v; ++run;
    }
    if (cur >= 0) {
        atomicAdd(&pooled[cur * HD + feat], acc);
        if (feat == 0) atomicAdd(&cntg[cur], (float)run);
    }
}

// ---------------- head: mean -> relu(W1) -> W2 -> log_softmax ----------------

__global__ __launch_bounds__(128) void k_head(const float* __restrict__ pooled,
                                              const float* __restrict__ cntg,
                                              const float* __restrict__ w1,
                                              const float* __restrict__ b1,
                                              const float* __restrict__ w2,
                                              const float* __restrict__ b2,
                                              float* __restrict__ out) {
    __shared__ float row[HD], hrow[HD], logits[CC];
    int g = blockIdx.x, t = threadIdx.x;
    row[t] = pooled[g * HD + t] / fmaxf(cntg[g], 1.f);
    __syncthreads();
    float acc = b1[t];
    for (int k = 0; k < HD; ++k) acc = fmaf(row[k], w1[k * HD + t], acc);
    hrow[t] = fmaxf(acc, 0.f);
    __syncthreads();
    if (t < CC) {
        float a = b2[t];
        for (int k = 0; k < HD; ++k) a = fmaf(hrow[k], w2[k * CC + t], a);
        logits[t] = a;
    }
    __syncthreads();
    if (t < CC) {
        float m = logits[0];
        for (int i = 1; i < CC; ++i) m = fmaxf(m, logits[i]);
        float s = 0.f;
        for (int i = 0; i < CC; ++i) s += expf(logits[i] - m);
        out[g * CC + t] = logits[t] - m - logf(s);
    }
}

// ---------------- launch ----------------

extern "C" void kernel_launch(void* const* d_in, const int* in_sizes, int n_in,
                              void* d_out, int out_size, void* d_ws, size_t ws_size,
                              hipStream_t stream) {
    const float* x      = (const float*)d_in[0];
    const int*   ei     = (const int*)d_in[1];   // [2,E]: row0=src, row1=dst
    const int*   batch  = (const int*)d_in[2];
    const float* w_init = (const float*)d_in[3];
    const float* b_init = (const float*)d_in[4];
    const float* w_conv = (const float*)d_in[5];  // [2,128,128]
    const float* b_conv = (const float*)d_in[6];  // [2,128]
    const float* w_h1   = (const float*)d_in[7];
    const float* b_h1   = (const float*)d_in[8];
    const float* w_h2   = (const float*)d_in[9];
    const float* b_h2   = (const float*)d_in[10];
    float* out = (float*)d_out;
    (void)n_in; (void)in_sizes; (void)out_size; (void)ws_size;

    char* ws = (char*)d_ws;
    size_t off = 0;
    auto alloc = [&](size_t bytes) -> void* {
        void* p = ws + off;
        off += (bytes + 255) & ~(size_t)255;
        return p;
    };
    unsigned short* hAbf         = (unsigned short*)alloc((size_t)NN * HD * 2);  // bf16 node state
    unsigned*       g8           = (unsigned*)alloc((size_t)NN * 32 * 4);        // fp8 messages 12.8MB
    unsigned short* Wt           = (unsigned short*)alloc(3 * 16384 * 2);
    float*          dinv         = (float*)alloc((size_t)NN * 4);
    int*            row_start    = (int*)alloc((size_t)(NN + 1) * 4);
    int*            col          = (int*)alloc((size_t)EE * 4);
    unsigned*       ebuf         = (unsigned*)alloc((size_t)EE * 4);             // packed 6.4MB
    unsigned*       bucket_cnt   = (unsigned*)alloc(256 * 4);
    unsigned*       bucket_start = (unsigned*)alloc(257 * 4);
    unsigned*       cursor       = (unsigned*)alloc(256 * 4);
    float*          pooled       = (float*)alloc((size_t)GG * HD * 4);
    float*          cntg         = (float*)alloc((size_t)GG * 4);

    const int* srcp = ei;
    const int* dstp = ei + EE;

    hipMemsetAsync(bucket_cnt, 0, 256 * 4, stream);
    hipMemsetAsync(pooled, 0, (size_t)GG * HD * 4, stream);
    hipMemsetAsync(cntg, 0, (size_t)GG * 4, stream);

    int nchunks = (EE + CH - 1) / CH;  // 391
    k_bhist<<<nchunks, 256, 0, stream>>>(dstp, bucket_cnt);
    k_bscan<<<1, 256, 0, stream>>>(bucket_cnt, bucket_start, cursor, row_start);
    k_bscatter<<<nchunks, 256, 0, stream>>>(srcp, dstp, cursor, ebuf);
    k_bucket_csr<<<NBK, 512, 0, stream>>>(ebuf, bucket_start, row_start, dinv, col);

    k_prep_w<<<192, 256, 0, stream>>>(w_init, w_conv, w_conv + HD * HD, Wt);

    int gemm_grid = (NN + 127) / 128;  // 782
    int agg_grid = NN / 8;             // 12500 (exact)

    // layer 1 (f32 input)
    k_gemm_mfma<true><<<gemm_grid, 256, 0, stream>>>(x, Wt, dinv, g8);
    k_aggregate<<<agg_grid, 256, 0, stream>>>(g8, row_start, col, dinv, b_init, (uint2*)hAbf);
    // layer 2
    k_gemm_mfma<false><<<gemm_grid, 256, 0, stream>>>(hAbf, Wt + 16384, dinv, g8);
    k_aggregate<<<agg_grid, 256, 0, stream>>>(g8, row_start, col, dinv, b_conv, (uint2*)hAbf);
    // layer 3
    k_gemm_mfma<false><<<gemm_grid, 256, 0, stream>>>(hAbf, Wt + 2 * 16384, dinv, g8);
    k_aggregate<<<agg_grid, 256, 0, stream>>>(g8, row_start, col, dinv, b_conv + HD, (uint2*)hAbf);

    k_pool_partial<<<(NN + 127) / 128, 256, 0, stream>>>(hAbf, batch, pooled, cntg);
    k_head<<<GG, 128, 0, stream>>>(pooled, cntg, w_h1, b_h1, w_h2, b_h2, out);
}